// Round 8
// baseline (446.106 us; speedup 1.0000x reference)
//
#include <hip/hip_runtime.h>
#include <hip/hip_bf16.h>
#include <math.h>

// ---------------------------------------------------------------------------
// B=2, S=4096, D=256, IN=768, N_BASIS=8, spline grid h=0.4
// view_emb adds a row-constant to pre-softmax scores -> cancelled -> unused.
// Softmax without max-subtraction: |q.k|/16 <= ~1.7 -> exp in [0.2,5.5] ->
// online softmax is LINEAR: O = sum exp(s)v, l = sum exp(s).
// R18: R17 still 1 block/CU (occupancy 22%): 2x80KB = exactly 160KB was
// refused (zero headroom), and qreg alone needs 128 VGPR = the whole cap ->
// Q was AGPR-shuffled/remat'd per tile. Fix both by halving the wave tile:
// Q-tile 64 rows/block (wm = 32-row half), grid (64,24). Per wave:
// qreg[2][8]=64 + oacc[2][4]=32 -> ~128 natural = cap (Q truly in regs).
// LDS = Ks 32K + Vs 32K + Ps 8K = 72KB -> 2 blocks/CU (144KB, headroom).
// Split staging (proven R16/R17): K(t+1) after mid barrier (drain under PV),
// V(t+1) after end barrier (drain under next S). Ps granule swizzle
// p=(k>>3)^(2*((r>>2)&3)) row-offset-invariant -> carries over verbatim.
// R13: fused layout 169.1MB; attp partials bf16. R11: sched_barrier pins.
// ---------------------------------------------------------------------------

typedef __hip_bfloat16 bf16;
using bf16x8 = __attribute__((ext_vector_type(8))) __bf16;
using f32x4  = __attribute__((ext_vector_type(4))) float;

__device__ __forceinline__ void load_lds16(const void* g, void* l) {
  __builtin_amdgcn_global_load_lds((__attribute__((address_space(1))) void*)g,
                                   (__attribute__((address_space(3))) void*)l,
                                   16, 0, 0);
}

__device__ __forceinline__ float wave_sum(float v) {
#pragma unroll
  for (int o = 32; o > 0; o >>= 1) v += __shfl_down(v, o, 64);
  return v;
}

__device__ __forceinline__ float to_f32(float v) { return v; }
__device__ __forceinline__ float to_f32(bf16 v) { return __bfloat162float(v); }

// closed-form cardinal cubic B-spline segment (validated R7)
__device__ __forceinline__ float b3_cardinal(float x, float tofs) {
  const float t = fmaf(x, 2.5f, tofs);
  const float tc = fminf(fmaxf(t, 0.0f), 4.0f);
  const float p2 = fmaxf(tc - 1.0f, 0.0f);
  const float p3 = fmaxf(tc - 2.0f, 0.0f);
  const float p4 = fmaxf(tc - 3.0f, 0.0f);
  return (tc * tc * tc - 4.0f * p2 * p2 * p2 + 6.0f * p3 * p3 * p3 -
          4.0f * p4 * p4 * p4) * (1.0f / 6.0f);
}

// ---------------------------------------------------------------------------
// bf16 MFMA GEMM, BT form, BK=64 (unchanged, proven): used by QKV + KAN
// (+ scores/PV in the non-fused fallback path).
// ---------------------------------------------------------------------------
template <typename OutT, bool EXP>
__global__ __launch_bounds__(256) void mfma_gemm_bt(
    const bf16* __restrict__ A, const bf16* __restrict__ B,
    const float* __restrict__ bias, OutT* __restrict__ C,
    float* __restrict__ lpart, int K, int lda, int ldb, int ldc, int zshift,
    size_t zAh, size_t zAl, size_t zBh, size_t zBl, size_t zC, size_t zL,
    float scale) {
  __shared__ __align__(16) bf16 As[8192];  // 128 x 64
  __shared__ __align__(16) bf16 Bs[8192];
  const int tid = (int)threadIdx.x;
  const int lane = tid & 63;
  const int w = tid >> 6;
  const int m0 = (int)blockIdx.y << 7;
  const int n0 = (int)blockIdx.x << 7;
  const size_t z = blockIdx.z;
  const size_t zlo = z & (((size_t)1 << zshift) - 1);
  A += (z >> zshift) * zAh + zlo * zAl;
  B += (z >> zshift) * zBh + zlo * zBl;
  C += z * zC;
  if (EXP) lpart += z * zL;

  // staging geometry
  const int srow8 = lane >> 3;  // row within 8-row chunk
  const int g8 = (lane & 4) | ((lane & 3) ^ ((lane >> 4) & 3));
  const bf16* gA[4];
  const bf16* gB[4];
  bf16* lA[4];
  bf16* lB[4];
#pragma unroll
  for (int j = 0; j < 4; ++j) {
    const int c = w + 4 * j;
    gA[j] = A + (size_t)(m0 + c * 8 + srow8) * lda + g8 * 8;
    gB[j] = B + (size_t)(n0 + c * 8 + srow8) * ldb + g8 * 8;
    lA[j] = As + c * 512;
    lB[j] = Bs + c * 512;
  }

  // fragment geometry
  const int m15 = lane & 15, quad = lane >> 4;
  const int fq = quad ^ ((m15 >> 1) & 3);
  const bf16* pA = As + (size_t)(((w >> 1) << 6) + m15) * 64 + fq * 8;
  const bf16* pB = Bs + (size_t)(((w & 1) << 6) + m15) * 64 + fq * 8;

  f32x4 acc[4][4];
#pragma unroll
  for (int mi = 0; mi < 4; ++mi)
#pragma unroll
    for (int ni = 0; ni < 4; ++ni) acc[mi][ni] = (f32x4)(0.0f);

  for (int k0 = 0; k0 < K; k0 += 64) {
#pragma unroll
    for (int j = 0; j < 4; ++j) {
      load_lds16(gA[j], lA[j]);
      load_lds16(gB[j], lB[j]);
      gA[j] += 64;
      gB[j] += 64;
    }
    __syncthreads();
    __builtin_amdgcn_sched_barrier(0);  // ds_reads must not hoist above barrier
    bf16x8 av[4][2], bv[4][2];
#pragma unroll
    for (int mi = 0; mi < 4; ++mi)
#pragma unroll
      for (int sub = 0; sub < 2; ++sub) {
        av[mi][sub] = *(const bf16x8*)(pA + mi * 1024 + sub * 32);
        bv[mi][sub] = *(const bf16x8*)(pB + mi * 1024 + sub * 32);
      }
#pragma unroll
    for (int sub = 0; sub < 2; ++sub)
#pragma unroll
      for (int mi = 0; mi < 4; ++mi)
#pragma unroll
        for (int ni = 0; ni < 4; ++ni)
          acc[mi][ni] = __builtin_amdgcn_mfma_f32_16x16x32_bf16(
              av[mi][sub], bv[ni][sub], acc[mi][ni], 0, 0, 0);
    __builtin_amdgcn_sched_barrier(0);  // reads/MFMAs must not sink below
    __syncthreads();
    __builtin_amdgcn_sched_barrier(0);  // next-iter LDS-DMA must not hoist
  }

  const int crow = m0 + ((w >> 1) << 6) + quad * 4;
  const int ccol = n0 + ((w & 1) << 6) + m15;
  float rs[4][4] = {};
#pragma unroll
  for (int ni = 0; ni < 4; ++ni) {
    const int col = ccol + ni * 16;
    const float bb = bias ? bias[col] : 0.0f;
#pragma unroll
    for (int mi = 0; mi < 4; ++mi) {
#pragma unroll
      for (int i = 0; i < 4; ++i) {
        const int row = crow + mi * 16 + i;
        float v = acc[mi][ni][i] * scale + bb;
        if constexpr (EXP) {
          v = __expf(v);
          rs[mi][i] += v;
        }
        if constexpr (sizeof(OutT) == 2)
          C[(size_t)row * ldc + col] = __float2bfloat16(v);
        else
          C[(size_t)row * ldc + col] = v;
      }
    }
  }
  if constexpr (EXP) {
    const int ch = ((int)blockIdx.x << 1) | (w & 1);
#pragma unroll
    for (int mi = 0; mi < 4; ++mi)
#pragma unroll
      for (int i = 0; i < 4; ++i) {
        float sv = rs[mi][i];
        sv += __shfl_xor(sv, 1);
        sv += __shfl_xor(sv, 2);
        sv += __shfl_xor(sv, 4);
        sv += __shfl_xor(sv, 8);
        if (m15 == 0)
          lpart[(size_t)ch * 4096 + crow + mi * 16 + i] = sv;
      }
  }
}

// ---------------------------------------------------------------------------
// R18 fused flash attention (linear online softmax, no rescale needed).
// Block: 512 thr = 8 waves (2 wm x 4 wn), Q-tile 64 rows (wm = 32-row half).
// KV-split 1024 keys = 16 tiles x 64 keys. grid = (64 Qtiles, 24).
// LDS 72KB (Ks 32K + Vs 32K + Ps 8K) -> 2 blocks/CU at VGPR<=128.
// Per wave: qreg[2][8] (64 VGPR, truly resident) + oacc[2][4] (32).
// Single K/V buffers; K(t+1) staged after mid barrier (drain hidden under
// PV), V(t+1) staged after end barrier (drain hidden under next S). Ps
// [64][64] granule swizzle p=(k>>3)^(2*((r>>2)&3)): conflict-free r/w.
// Outputs: attp bf16 partials + lpart 16 ch/(batch,view).
// ---------------------------------------------------------------------------
__global__ __launch_bounds__(512, 2) void fused_attn(
    const bf16* __restrict__ qkv, const bf16* __restrict__ vT,
    bf16* __restrict__ attp, float* __restrict__ lpart) {
  __shared__ __align__(16) bf16 Ks[16384];  // 4 subtiles 64(keys)x64(k)
  __shared__ __align__(16) bf16 Vs[16384];  // 4 rowgroups 64(d)x64(key)
  __shared__ __align__(16) bf16 Ps[4096];   // 64 x 64, granule-swizzled
  const int tid = (int)threadIdx.x;
  const int lane = tid & 63;
  const int w = tid >> 6;   // 0..7
  const int wm = w >> 2;    // 0..1 : Q-row 32-half
  const int wn = w & 3;     // 0..3 : S key-16-col / O d-64-col
  const int bx = (int)blockIdx.x;           // Q-tile (64 rows)
  const int by = (int)blockIdx.y;           // v*8 + b*4 + sp
  const int v = by >> 3, b = (by >> 2) & 1, sp = by & 3;
  const bf16* qb = qkv + (size_t)((v * 2 + b) * 4096) * 768;
  const bf16* vb = vT + (size_t)(v * 2 + b) * 1048576;
  attp += (size_t)by * 1048576;

  const int srow8 = lane >> 3;
  const int g8 = (lane & 4) | ((lane & 3) ^ ((lane >> 4) & 3));
  const int m15 = lane & 15, quad = lane >> 4;
  const int fq = quad ^ ((m15 >> 1) & 3);
  const int key0 = sp * 1024;

  // staging bases (chunk c = w of each 64x64 subtile)
  const bf16* gKb = qb + (size_t)(key0 + w * 8 + srow8) * 768 + 256 + g8 * 8;
  const bf16* gVb = vb + (size_t)(w * 8 + srow8) * 4096 + key0 + g8 * 8;

#define STAGE_K(T)                                               \
  do {                                                           \
    const bf16* gk_ = gKb + (size_t)(T) * 49152;                 \
    bf16* lk_ = Ks + w * 512;                                    \
    _Pragma("unroll") for (int j_ = 0; j_ < 4; ++j_)             \
        load_lds16(gk_ + j_ * 64, lk_ + j_ * 4096);              \
  } while (0)
#define STAGE_V(T)                                               \
  do {                                                           \
    const bf16* gv_ = gVb + (T) * 64;                            \
    bf16* lv_ = Vs + w * 512;                                    \
    _Pragma("unroll") for (int j_ = 0; j_ < 4; ++j_)             \
        load_lds16(gv_ + (size_t)j_ * 262144, lv_ + j_ * 4096);  \
  } while (0)

  STAGE_K(0);
  STAGE_V(0);

  // Q in registers: qreg[mf][ks] = Q[qrow+mf*16][ks*32+quad*8 ..+8]
  bf16x8 qreg[2][8];
  const int qrow = bx * 64 + wm * 32 + m15;
#pragma unroll
  for (int mf = 0; mf < 2; ++mf)
#pragma unroll
    for (int ks = 0; ks < 8; ++ks)
      qreg[mf][ks] = *(const bf16x8*)(qb + (size_t)(qrow + mf * 16) * 768 +
                                      ks * 32 + quad * 8);

  f32x4 oacc[2][4];
#pragma unroll
  for (int mi = 0; mi < 2; ++mi)
#pragma unroll
    for (int ni = 0; ni < 4; ++ni) oacc[mi][ni] = (f32x4)(0.0f);
  float rs[2][4] = {};

  __syncthreads();  // drain tile-0 K/V DMAs + qreg loads
  __builtin_amdgcn_sched_barrier(0);

  const bf16* pKr = Ks + (wn * 16 + m15) * 64 + fq * 8;
  const bf16* pVr = Vs + wn * 4096 + m15 * 64 + fq * 8;
  // P write: row r = wm*32 + mf*16 + quad*4 + i, col k = wn*16 + m15;
  // granule p = (k>>3) ^ (2*((r>>2)&3)) = gP ^ (quad<<1)  (wm,mf,i drop out)
  const int gP = wn * 2 + (m15 >> 3);
  bf16* pPw = Ps + (wm * 32 + quad * 4) * 64 + ((gP ^ (quad << 1)) << 3) +
              (m15 & 7);
  // P read: row r = wm*32 + m15 + mi*16 -> (r>>2)&3 = (m15>>2)&3
  const int xr = ((m15 >> 2) & 3) << 1;
  const bf16* pPr = Ps + (wm * 32 + m15) * 64;

  for (int t = 0; t < 16; ++t) {
    // ---- S phase: sacc[mf] = Q @ K^T, wave tile 32 rows x 16 keys
    f32x4 sacc[2];
#pragma unroll
    for (int mf = 0; mf < 2; ++mf) sacc[mf] = (f32x4)(0.0f);
#pragma unroll
    for (int ks = 0; ks < 8; ++ks) {
      const bf16x8 bvk =
          *(const bf16x8*)(pKr + (ks >> 1) * 4096 + (ks & 1) * 32);
#pragma unroll
      for (int mf = 0; mf < 2; ++mf)
        sacc[mf] = __builtin_amdgcn_mfma_f32_16x16x32_bf16(qreg[mf][ks], bvk,
                                                           sacc[mf], 0, 0, 0);
    }
    // ---- exp + P write (swizzled, conflict-free) + row-sum accumulate
#pragma unroll
    for (int mf = 0; mf < 2; ++mf)
#pragma unroll
      for (int i = 0; i < 4; ++i) {
        const float pe = exp2f(sacc[mf][i] * 0.09016844136f);  // /16 * log2 e
        rs[mf][i] += pe;
        pPw[mf * 1024 + i * 64] = __float2bfloat16(pe);
      }
    __builtin_amdgcn_sched_barrier(0);
    __syncthreads();  // mid: Ps visible; Ks(t) dead; V(t) DMA long drained
    __builtin_amdgcn_sched_barrier(0);
    if (t < 15) STAGE_K(t + 1);  // drains at end barrier, hidden under PV
    // ---- PV: oacc += P @ V ; wave tile 32 rows x 64 d
#pragma unroll
    for (int sub = 0; sub < 2; ++sub) {
      bf16x8 pa[2], bvv[4];
#pragma unroll
      for (int mi = 0; mi < 2; ++mi)
        pa[mi] = *(const bf16x8*)(pPr + mi * 1024 +
                                  ((((sub << 2) | quad) ^ xr) << 3));
#pragma unroll
      for (int ni = 0; ni < 4; ++ni)
        bvv[ni] = *(const bf16x8*)(pVr + ni * 1024 + sub * 32);
#pragma unroll
      for (int mi = 0; mi < 2; ++mi)
#pragma unroll
        for (int ni = 0; ni < 4; ++ni)
          oacc[mi][ni] = __builtin_amdgcn_mfma_f32_16x16x32_bf16(
              pa[mi], bvv[ni], oacc[mi][ni], 0, 0, 0);
    }
    __builtin_amdgcn_sched_barrier(0);
    __syncthreads();  // end: Vs(t)+Ps dead; K(t+1) DMA drained here
    __builtin_amdgcn_sched_barrier(0);
    if (t < 15) STAGE_V(t + 1);  // drains at next mid barrier, hidden under S
  }
#undef STAGE_K
#undef STAGE_V

  // ---- epilogue: O partials (bf16) + lpart channel (b*16 + sp*4 + wn)
  const int crow0 = bx * 64 + wm * 32 + quad * 4;
  const int ccol0 = wn * 64 + m15;
#pragma unroll
  for (int mi = 0; mi < 2; ++mi)
#pragma unroll
    for (int ni = 0; ni < 4; ++ni)
#pragma unroll
      for (int i = 0; i < 4; ++i)
        attp[(size_t)(crow0 + mi * 16 + i) * 256 + ccol0 + ni * 16] =
            __float2bfloat16(oacc[mi][ni][i]);
  float* lp = lpart + (size_t)v * 131072 +
              (size_t)(b * 16 + sp * 4 + wn) * 4096 + bx * 64 + wm * 32;
#pragma unroll
  for (int mf = 0; mf < 2; ++mf)
#pragma unroll
    for (int i = 0; i < 4; ++i) {
      float sv = rs[mf][i];
      sv += __shfl_xor(sv, 1);
      sv += __shfl_xor(sv, 2);
      sv += __shfl_xor(sv, 4);
      sv += __shfl_xor(sv, 8);
      if (m15 == 0) lp[mf * 16 + quad * 4 + i] = sv;
    }
}

// ---------------------------------------------------------------------------
// residual + LayerNorm from split-K PV partials and lpart row sums.
// PT = partial dtype: bf16 (fused) / float (fallback). nch lpart channels.
// FUSE=true : emit 9 bf16 KAN basis channels directly (no x buffer).
// ---------------------------------------------------------------------------
template <bool FUSE, typename PT>
__global__ __launch_bounds__(256) void resid_ln_kernel(
    const PT* __restrict__ attp, const float* __restrict__ lpart,
    const float* __restrict__ tok, const float* __restrict__ gamma,
    const float* __restrict__ beta, float* __restrict__ xout,
    bf16* __restrict__ basis, int nch, int vIdx) {
  __shared__ float red[4];
  __shared__ float sinvl;
  __shared__ __align__(16) bf16 st[2304];  // 256 elems x 9 channels
  const int n = (int)blockIdx.x;  // 0..8191 ; b = n>>12
  const int d = (int)threadIdx.x;
  const int b = n >> 12, r = n & 4095;
  float ls = 0.f;
  if (d < nch) ls = lpart[((size_t)(b * nch + d)) * 4096 + r];
  ls = wave_sum(ls);
  if (d == 0) sinvl = 1.0f / ls;
  const size_t abase = (size_t)(b * 4) * 1048576 + (size_t)r * 256 + d;
  const float asum = to_f32(attp[abase]) + to_f32(attp[abase + 1048576]) +
                     to_f32(attp[abase + 2097152]) +
                     to_f32(attp[abase + 3145728]);
  __syncthreads();
  const float y = asum * sinvl + tok[(size_t)n * 256 + d];
  float s = wave_sum(y);
  if ((d & 63) == 0) red[d >> 6] = s;
  __syncthreads();
  const float mu = (red[0] + red[1] + red[2] + red[3]) * (1.0f / 256.0f);
  __syncthreads();
  const float c = y - mu;
  float s2 = wave_sum(c * c);
  if ((d & 63) == 0) red[d >> 6] = s2;
  __syncthreads();
  const float var = (red[0] + red[1] + red[2] + red[3]) * (1.0f / 256.0f);
  const float rstd = rsqrtf(var + 1e-5f);
  const float val = c * rstd * gamma[d] + beta[d];
  if constexpr (!FUSE) {
    xout[(size_t)n * 768 + vIdx * 256 + d] = val;
  } else {
#pragma unroll
    for (int f = 0; f < 8; ++f)
      st[d * 9 + f] = __float2bfloat16(b3_cardinal(val, 5.5f - (float)f));
    st[d * 9 + 8] = __float2bfloat16(val / (1.0f + __expf(-val)));
    __syncthreads();
    float4* gb = (float4*)((char*)basis + (size_t)n * 13824 + vIdx * 4608);
    const float4* sb = (const float4*)st;
    gb[d] = sb[d];
    if (d < 32) gb[256 + d] = sb[256 + d];
  }
}

// ---------------------------------------------------------------------------
__global__ __launch_bounds__(256) void prep_w(
    const float* __restrict__ bw, const float* __restrict__ sw,
    const float* __restrict__ scaler, bf16* __restrict__ Wmat) {
  const int o = blockIdx.x;
  for (int ii = 0; ii < 3; ++ii) {
    const int i = ii * 256 + (int)threadIdx.x;
    const float s = scaler[(size_t)o * 768 + i];
    bf16* p = Wmat + (size_t)o * 6912 + i * 9;
    const float* swp = sw + ((size_t)o * 768 + i) * 8;
#pragma unroll
    for (int f = 0; f < 8; ++f) p[f] = __float2bfloat16(swp[f] * s);
    p[8] = __float2bfloat16(bw[(size_t)o * 768 + i]);
  }
}

__global__ __launch_bounds__(256) void prep_qkvw(
    const float* __restrict__ wq, const float* __restrict__ wk,
    const float* __restrict__ wv, const float* __restrict__ bq,
    const float* __restrict__ bk, const float* __restrict__ bv,
    bf16* __restrict__ wqkvb, float* __restrict__ bqkv) {
  const int idx = blockIdx.x * 256 + (int)threadIdx.x;
  const int row = idx >> 8, col = idx & 255;
  const float* src = row < 256 ? wq : (row < 512 ? wk : wv);
  wqkvb[idx] = __float2bfloat16(src[((row & 255) << 8) + col]);
  if (idx < 768)
    bqkv[idx] = idx < 256 ? bq[idx] : (idx < 512 ? bk[idx - 256] : bv[idx - 512]);
}

__global__ __launch_bounds__(256) void cast_tok3(
    const float4* __restrict__ t0, const float4* __restrict__ t1,
    const float4* __restrict__ t2, bf16* __restrict__ dst) {
  const int vv = blockIdx.y;
  const float4* src = vv == 0 ? t0 : (vv == 1 ? t1 : t2);
  const int idx = blockIdx.x * 256 + (int)threadIdx.x;
  const float4 val = src[idx];
  bf16* p = dst + (size_t)vv * 2097152 + (size_t)idx * 4;
  p[0] = __float2bfloat16(val.x);
  p[1] = __float2bfloat16(val.y);
  p[2] = __float2bfloat16(val.z);
  p[3] = __float2bfloat16(val.w);
}

// vT[z][d][s] = qkv[z*4096+s][512+d]
__global__ __launch_bounds__(256) void transpose_v(
    const bf16* __restrict__ qkv, bf16* __restrict__ vT) {
  __shared__ bf16 tle[64][65];
  const int s0 = blockIdx.x << 6, d0 = blockIdx.y << 6, z = blockIdx.z;
  const int tid = (int)threadIdx.x;
  const int c = tid & 63, rr = tid >> 6;
  for (int r = 0; r < 64; r += 4)
    tle[r + rr][c] = qkv[(size_t)(z * 4096 + s0 + r + rr) * 768 + 512 + d0 + c];
  __syncthreads();
  for (int r = 0; r < 64; r += 4)
    vT[(size_t)z * 1048576 + (size_t)(d0 + r + rr) * 4096 + s0 + c] =
        tle[c][r + rr];
}

// ---------------------------------------------------------------------------
// fallback basis: basis[n][i*9+f] from x (Cox-de-Boor, proven R6)
// ---------------------------------------------------------------------------
__global__ __launch_bounds__(256) void basis_kernel(
    const float* __restrict__ x, bf16* __restrict__ basis) {
  const int i = blockIdx.x * 256 + (int)threadIdx.x;  // 0..767
  const int n = blockIdx.y;
  const float xv = x[(size_t)n * 768 + i];
  float b[11];
#pragma unroll
  for (int m = 0; m < 11; ++m) {
    const float g0 = 0.4f * (float)(m - 3) - 1.0f;
    const float g1 = 0.4f * (float)(m - 2) - 1.0f;
    b[m] = (xv >= g0 && xv < g1) ? 1.0f : 0.0f;
  }
#pragma unroll
  for (int k = 1; k <= 3; ++k) {
    const float inv = 1.0f / (0.4f * (float)k);
#pragma unroll
    for (int m = 0; m + k < 11; ++m) {
      const float gm = 0.4f * (float)(m - 3) - 1.0f;
      const float gmk1 = 0.4f * (float)(m + k - 2) - 1.0f;
      b[m] = (xv - gm) * inv * b[m] + (gmk1 - xv) * inv * b[m + 1];
    }
  }
  bf16* p = basis + (size_t)n * 6912 + i * 9;
#pragma unroll
  for (int f = 0; f < 8; ++f) p[f] = __float2bfloat16(b[f]);
  p[8] = __float2bfloat16(xv / (1.0f + __expf(-xv)));
}

__global__ __launch_bounds__(256) void combine4_kernel(
    const float4* __restrict__ p, float4* __restrict__ out) {
  const int idx = blockIdx.x * 256 + (int)threadIdx.x;
  const float4 a = p[idx];
  const float4 b = p[idx + 524288];
  const float4 c = p[idx + 1048576];
  const float4 d = p[idx + 1572864];
  out[idx] =
      make_float4(a.x + b.x + c.x + d.x, a.y + b.y + c.y + d.y,
                  a.z + b.z + c.z + d.z, a.w + b.w + c.w + d.w);
}

__global__ __launch_bounds__(256) void combine6_kernel(
    const float4* __restrict__ p, float4* __restrict__ out) {
  const int idx = blockIdx.x * 256 + (int)threadIdx.x;
  float4 s = p[idx];
#pragma unroll
  for (int j = 1; j < 6; ++j) {
    const float4 a = p[idx + (size_t)j * 524288];
    s.x += a.x;
    s.y += a.y;
    s.z += a.z;
    s.w += a.w;
  }
  out[idx] = s;
}

// ---------------------------------------------------------------------------
extern "C" void kernel_launch(void* const* d_in, const int* in_sizes, int n_in,
                              void* d_out, int out_size, void* d_ws,
                              size_t ws_size, hipStream_t stream) {
  const float* tok[3] = {(const float*)d_in[0], (const float*)d_in[1],
                         (const float*)d_in[2]};
  const float* wq = (const float*)d_in[3];
  const float* bq = (const float*)d_in[4];
  const float* wk = (const float*)d_in[5];
  const float* bk = (const float*)d_in[6];
  const float* wv = (const float*)d_in[7];
  const float* bv = (const float*)d_in[8];
  // d_in[9] view_emb unused (softmax-invariant)
  const float* lng[3] = {(const float*)d_in[10], (const float*)d_in[12],
                         (const float*)d_in[14]};
  const float* lnb[3] = {(const float*)d_in[11], (const float*)d_in[13],
                         (const float*)d_in[15]};
  const float* bw = (const float*)d_in[16];
  const float* sw = (const float*)d_in[17];
  const float* scaler = (const float*)d_in[18];

  // fused layout (R13, total 169,085,952 B <= known-safe 194,776,064):
  //   basis @0 (113,246,208) -- written by resid_ln AFTER attention; until
  //     then sub-aliased: tokb @0 (12.58M) | qkv @12,582,912 (37.75M) |
  //     vT @50,331,648 (12.58M, ends 62,914,560)
  //   attb (bf16 partials, 24 x 2,097,152 B) @113,246,208 -> 163,577,856
  //   lpart_f @163,577,856 (1.57M) -> 165,150,720
  //   Wmat @165,150,720 (3.54M) | wqkvb @168,689,664 | bqkv @169,082,880
  //   pout (KAN z=6, 50,331,648 B fp32) aliases attb (dead after resid_ln)
  // fallback (unchanged): Pb @62,914,560 | lpart @130,023,424 |
  //   attp @132,120,576 | x @165,675,008 | basis aliases [0,..) |
  //   Wmat @190,840,832 | pout aliases attp.
  const bool fused = ws_size >= 169085952ull;
  char* w8 = (char*)d_ws;
  bf16* tokb = (bf16*)(w8 + 0);
  bf16* qkv = (bf16*)(w8 + 12582912);
  bf16* vT = (bf16*)(w8 + 50331648);
  float* x;
  bf16* basis;
  bf16* Wmat;
  float* pout;
  // fallback pointers
  bf16* Pb = (bf16*)(w8 + 62914560);
  float* lpart = (float*)(w8 + 130023424);
  float* attp = (float*)(w8 + 132120576);
  // fused pointers
  bf16* attb = (bf16*)(w8 + 113246208);
  float* lpart_f = (float*)(w8 + 163577856);
  if (fused) {
    x = nullptr;
    basis = (bf16*)(w8 + 0);
    Wmat = (bf16*)(w8 + 165150720);
    pout = (float*)(w8 + 113246208);  // attb dead after resid_ln
  } else {
    x = (float*)(w8 + 165675008);
    basis = (bf16*)(w8 + 0);
    Wmat = (bf16*)(w8 + 190840832);
    pout = attp;  // 4 x 8.39 MB, attp dead
  }
  bf16* wqkvb = (bf16*)((char*)Wmat + 3538944);
  float* bqkv = (float*)((char*)wqkvb + 393216);

  prep_w<<<256, 256, 0, stream>>>(bw, sw, scaler, Wmat);
  prep_qkvw<<<768, 256, 0, stream>>>(wq, wk, wv, bq, bk, bv, wqkvb, bqkv);
  cast_tok3<<<dim3(2048, 3), 256, 0, stream>>>(
      (const float4*)tok[0], (const float4*)tok[1], (const float4*)tok[2],
      tokb);

  // QKV all views: [24576,256] @ [768,256]^T + bias -> qkv bf16
  mfma_gemm_bt<bf16, false><<<dim3(6, 192, 1), 256, 0, stream>>>(
      tokb, wqkvb, bqkv, qkv, nullptr, 256, 256, 256, 768, 1, 0, 0, 0, 0, 0,
      0, 1.0f);
  transpose_v<<<dim3(64, 4, 6), 256, 0, stream>>>(qkv, vT);

  if (fused) {
    // fused flash attention: all views/batches/splits in one dispatch
    fused_attn<<<dim3(64, 24), 512, 0, stream>>>(qkv, vT, attb, lpart_f);
    for (int v = 0; v < 3; ++v)
      resid_ln_kernel<true, bf16><<<8192, 256, 0, stream>>>(
          attb + (size_t)v * 8388608, lpart_f + (size_t)v * 131072, tok[v],
          lng[v], lnb[v], nullptr, basis, 16, v);
    // KAN split-K=6 (z=6, 768 blocks = 3/CU): slice K=1152
    mfma_gemm_bt<float, false><<<dim3(2, 64, 6), 256, 0, stream>>>(
        basis, Wmat, nullptr, pout, nullptr, 1152, 6912, 6912, 256, 3, 0,
        1152, 0, 1152, 2097152, 0, 1.0f);
    combine6_kernel<<<2048, 256, 0, stream>>>((const float4*)pout,
                                              (float4*)d_out);
  } else {
    for (int v = 0; v < 3; ++v) {
      const bf16* qb = qkv + (size_t)(2 * v) * 4096 * 768;
      // scores both batches (z=2): P = exp(q@k^T/16) bf16 + lpart partials
      mfma_gemm_bt<bf16, true><<<dim3(32, 32, 2), 256, 0, stream>>>(
          qb, qb + 256, nullptr, Pb, lpart, 256, 768, 768, 4096, 1, 0,
          3145728, 0, 3145728, 16777216, 262144, 0.0625f);
      // PV split-K=4 x batch (z=8): attp[z] = P-slice @ vT-slice^T
      mfma_gemm_bt<float, false><<<dim3(2, 32, 8), 256, 0, stream>>>(
          Pb, vT + (size_t)(2 * v) * 1048576, nullptr, attp, nullptr, 1024,
          4096, 4096, 256, 2, 16777216, 1024, 1048576, 1024, 1048576, 0, 1.0f);
      resid_ln_kernel<false, float><<<8192, 256, 0, stream>>>(
          attp, lpart, tok[v], lng[v], lnb[v], x, nullptr, 64, v);
    }
    basis_kernel<<<dim3(3, 8192), 256, 0, stream>>>(x, basis);
    mfma_gemm_bt<float, false><<<dim3(2, 64, 4), 256, 0, stream>>>(
        basis, Wmat, nullptr, pout, nullptr, 1728, 6912, 6912, 256, 2, 0,
        1728, 0, 1728, 2097152, 0, 1.0f);
    combine4_kernel<<<2048, 256, 0, stream>>>((const float4*)pout,
                                              (float4*)d_out);
  }
}

// Round 9
// 444.991 us; speedup vs baseline: 1.0025x; 1.0025x over previous
//
#include <hip/hip_runtime.h>
#include <hip/hip_bf16.h>
#include <math.h>

// ---------------------------------------------------------------------------
// B=2, S=4096, D=256, IN=768, N_BASIS=8, spline grid h=0.4
// view_emb adds a row-constant to pre-softmax scores -> cancelled -> unused.
// Softmax without max-subtraction: |q.k|/16 <= ~1.7 -> exp in [0.2,5.5] ->
// online softmax is LINEAR: O = sum exp(s)v, l = sum exp(s).
// R19: the occupancy blocker was __launch_bounds__' SECOND ARG: every
// (512,2) build reads 22-23% occupancy (1 block/CU) regardless of LDS
// (112/80/72KB), while R16's (512,4) build read 34% (2 blocks, 2x80KB
// co-resident). hipcc pins waves/EU to the 2nd arg (pin, not floor). Fix:
// plain __launch_bounds__(512) on fused_attn — natural VGPR=80 (measured
// R18) allows 4+ waves/SIMD, LDS 2x72KB=144KB fits -> 2 blocks/CU by
// resources. R18 structure (Q-tile 64 rows, qreg[2][8] resident, 72KB LDS,
// split K/V staging, Ps granule swizzle) unchanged — passed correctness.
// R13: fused layout 169.1MB; attp partials bf16. R11: sched_barrier pins.
// ---------------------------------------------------------------------------

typedef __hip_bfloat16 bf16;
using bf16x8 = __attribute__((ext_vector_type(8))) __bf16;
using f32x4  = __attribute__((ext_vector_type(4))) float;

__device__ __forceinline__ void load_lds16(const void* g, void* l) {
  __builtin_amdgcn_global_load_lds((__attribute__((address_space(1))) void*)g,
                                   (__attribute__((address_space(3))) void*)l,
                                   16, 0, 0);
}

__device__ __forceinline__ float wave_sum(float v) {
#pragma unroll
  for (int o = 32; o > 0; o >>= 1) v += __shfl_down(v, o, 64);
  return v;
}

__device__ __forceinline__ float to_f32(float v) { return v; }
__device__ __forceinline__ float to_f32(bf16 v) { return __bfloat162float(v); }

// closed-form cardinal cubic B-spline segment (validated R7)
__device__ __forceinline__ float b3_cardinal(float x, float tofs) {
  const float t = fmaf(x, 2.5f, tofs);
  const float tc = fminf(fmaxf(t, 0.0f), 4.0f);
  const float p2 = fmaxf(tc - 1.0f, 0.0f);
  const float p3 = fmaxf(tc - 2.0f, 0.0f);
  const float p4 = fmaxf(tc - 3.0f, 0.0f);
  return (tc * tc * tc - 4.0f * p2 * p2 * p2 + 6.0f * p3 * p3 * p3 -
          4.0f * p4 * p4 * p4) * (1.0f / 6.0f);
}

// ---------------------------------------------------------------------------
// bf16 MFMA GEMM, BT form, BK=64 (unchanged, proven): used by QKV + KAN
// (+ scores/PV in the non-fused fallback path).
// ---------------------------------------------------------------------------
template <typename OutT, bool EXP>
__global__ __launch_bounds__(256) void mfma_gemm_bt(
    const bf16* __restrict__ A, const bf16* __restrict__ B,
    const float* __restrict__ bias, OutT* __restrict__ C,
    float* __restrict__ lpart, int K, int lda, int ldb, int ldc, int zshift,
    size_t zAh, size_t zAl, size_t zBh, size_t zBl, size_t zC, size_t zL,
    float scale) {
  __shared__ __align__(16) bf16 As[8192];  // 128 x 64
  __shared__ __align__(16) bf16 Bs[8192];
  const int tid = (int)threadIdx.x;
  const int lane = tid & 63;
  const int w = tid >> 6;
  const int m0 = (int)blockIdx.y << 7;
  const int n0 = (int)blockIdx.x << 7;
  const size_t z = blockIdx.z;
  const size_t zlo = z & (((size_t)1 << zshift) - 1);
  A += (z >> zshift) * zAh + zlo * zAl;
  B += (z >> zshift) * zBh + zlo * zBl;
  C += z * zC;
  if (EXP) lpart += z * zL;

  // staging geometry
  const int srow8 = lane >> 3;  // row within 8-row chunk
  const int g8 = (lane & 4) | ((lane & 3) ^ ((lane >> 4) & 3));
  const bf16* gA[4];
  const bf16* gB[4];
  bf16* lA[4];
  bf16* lB[4];
#pragma unroll
  for (int j = 0; j < 4; ++j) {
    const int c = w + 4 * j;
    gA[j] = A + (size_t)(m0 + c * 8 + srow8) * lda + g8 * 8;
    gB[j] = B + (size_t)(n0 + c * 8 + srow8) * ldb + g8 * 8;
    lA[j] = As + c * 512;
    lB[j] = Bs + c * 512;
  }

  // fragment geometry
  const int m15 = lane & 15, quad = lane >> 4;
  const int fq = quad ^ ((m15 >> 1) & 3);
  const bf16* pA = As + (size_t)(((w >> 1) << 6) + m15) * 64 + fq * 8;
  const bf16* pB = Bs + (size_t)(((w & 1) << 6) + m15) * 64 + fq * 8;

  f32x4 acc[4][4];
#pragma unroll
  for (int mi = 0; mi < 4; ++mi)
#pragma unroll
    for (int ni = 0; ni < 4; ++ni) acc[mi][ni] = (f32x4)(0.0f);

  for (int k0 = 0; k0 < K; k0 += 64) {
#pragma unroll
    for (int j = 0; j < 4; ++j) {
      load_lds16(gA[j], lA[j]);
      load_lds16(gB[j], lB[j]);
      gA[j] += 64;
      gB[j] += 64;
    }
    __syncthreads();
    __builtin_amdgcn_sched_barrier(0);  // ds_reads must not hoist above barrier
    bf16x8 av[4][2], bv[4][2];
#pragma unroll
    for (int mi = 0; mi < 4; ++mi)
#pragma unroll
      for (int sub = 0; sub < 2; ++sub) {
        av[mi][sub] = *(const bf16x8*)(pA + mi * 1024 + sub * 32);
        bv[mi][sub] = *(const bf16x8*)(pB + mi * 1024 + sub * 32);
      }
#pragma unroll
    for (int sub = 0; sub < 2; ++sub)
#pragma unroll
      for (int mi = 0; mi < 4; ++mi)
#pragma unroll
        for (int ni = 0; ni < 4; ++ni)
          acc[mi][ni] = __builtin_amdgcn_mfma_f32_16x16x32_bf16(
              av[mi][sub], bv[ni][sub], acc[mi][ni], 0, 0, 0);
    __builtin_amdgcn_sched_barrier(0);  // reads/MFMAs must not sink below
    __syncthreads();
    __builtin_amdgcn_sched_barrier(0);  // next-iter LDS-DMA must not hoist
  }

  const int crow = m0 + ((w >> 1) << 6) + quad * 4;
  const int ccol = n0 + ((w & 1) << 6) + m15;
  float rs[4][4] = {};
#pragma unroll
  for (int ni = 0; ni < 4; ++ni) {
    const int col = ccol + ni * 16;
    const float bb = bias ? bias[col] : 0.0f;
#pragma unroll
    for (int mi = 0; mi < 4; ++mi) {
#pragma unroll
      for (int i = 0; i < 4; ++i) {
        const int row = crow + mi * 16 + i;
        float v = acc[mi][ni][i] * scale + bb;
        if constexpr (EXP) {
          v = __expf(v);
          rs[mi][i] += v;
        }
        if constexpr (sizeof(OutT) == 2)
          C[(size_t)row * ldc + col] = __float2bfloat16(v);
        else
          C[(size_t)row * ldc + col] = v;
      }
    }
  }
  if constexpr (EXP) {
    const int ch = ((int)blockIdx.x << 1) | (w & 1);
#pragma unroll
    for (int mi = 0; mi < 4; ++mi)
#pragma unroll
      for (int i = 0; i < 4; ++i) {
        float sv = rs[mi][i];
        sv += __shfl_xor(sv, 1);
        sv += __shfl_xor(sv, 2);
        sv += __shfl_xor(sv, 4);
        sv += __shfl_xor(sv, 8);
        if (m15 == 0)
          lpart[(size_t)ch * 4096 + crow + mi * 16 + i] = sv;
      }
  }
}

// ---------------------------------------------------------------------------
// R19 fused flash attention (linear online softmax, no rescale needed).
// Block: 512 thr = 8 waves (2 wm x 4 wn), Q-tile 64 rows (wm = 32-row half).
// KV-split 1024 keys = 16 tiles x 64 keys. grid = (64 Qtiles, 24).
// LDS 72KB (Ks 32K + Vs 32K + Ps 8K); plain __launch_bounds__(512) — no
// waves/EU pin — so HW places 2 blocks/CU (VGPR~80 natural, 144KB LDS).
// Per wave: qreg[2][8] (64 VGPR, resident) + oacc[2][4] (32).
// Single K/V buffers; K(t+1) staged after mid barrier (drain hidden under
// PV), V(t+1) staged after end barrier (drain hidden under next S). Ps
// [64][64] granule swizzle p=(k>>3)^(2*((r>>2)&3)): conflict-free r/w.
// Outputs: attp bf16 partials + lpart 16 ch/(batch,view).
// ---------------------------------------------------------------------------
__global__ __launch_bounds__(512) void fused_attn(
    const bf16* __restrict__ qkv, const bf16* __restrict__ vT,
    bf16* __restrict__ attp, float* __restrict__ lpart) {
  __shared__ __align__(16) bf16 Ks[16384];  // 4 subtiles 64(keys)x64(k)
  __shared__ __align__(16) bf16 Vs[16384];  // 4 rowgroups 64(d)x64(key)
  __shared__ __align__(16) bf16 Ps[4096];   // 64 x 64, granule-swizzled
  const int tid = (int)threadIdx.x;
  const int lane = tid & 63;
  const int w = tid >> 6;   // 0..7
  const int wm = w >> 2;    // 0..1 : Q-row 32-half
  const int wn = w & 3;     // 0..3 : S key-16-col / O d-64-col
  const int bx = (int)blockIdx.x;           // Q-tile (64 rows)
  const int by = (int)blockIdx.y;           // v*8 + b*4 + sp
  const int v = by >> 3, b = (by >> 2) & 1, sp = by & 3;
  const bf16* qb = qkv + (size_t)((v * 2 + b) * 4096) * 768;
  const bf16* vb = vT + (size_t)(v * 2 + b) * 1048576;
  attp += (size_t)by * 1048576;

  const int srow8 = lane >> 3;
  const int g8 = (lane & 4) | ((lane & 3) ^ ((lane >> 4) & 3));
  const int m15 = lane & 15, quad = lane >> 4;
  const int fq = quad ^ ((m15 >> 1) & 3);
  const int key0 = sp * 1024;

  // staging bases (chunk c = w of each 64x64 subtile)
  const bf16* gKb = qb + (size_t)(key0 + w * 8 + srow8) * 768 + 256 + g8 * 8;
  const bf16* gVb = vb + (size_t)(w * 8 + srow8) * 4096 + key0 + g8 * 8;

#define STAGE_K(T)                                               \
  do {                                                           \
    const bf16* gk_ = gKb + (size_t)(T) * 49152;                 \
    bf16* lk_ = Ks + w * 512;                                    \
    _Pragma("unroll") for (int j_ = 0; j_ < 4; ++j_)             \
        load_lds16(gk_ + j_ * 64, lk_ + j_ * 4096);              \
  } while (0)
#define STAGE_V(T)                                               \
  do {                                                           \
    const bf16* gv_ = gVb + (T) * 64;                            \
    bf16* lv_ = Vs + w * 512;                                    \
    _Pragma("unroll") for (int j_ = 0; j_ < 4; ++j_)             \
        load_lds16(gv_ + (size_t)j_ * 262144, lv_ + j_ * 4096);  \
  } while (0)

  STAGE_K(0);
  STAGE_V(0);

  // Q in registers: qreg[mf][ks] = Q[qrow+mf*16][ks*32+quad*8 ..+8]
  bf16x8 qreg[2][8];
  const int qrow = bx * 64 + wm * 32 + m15;
#pragma unroll
  for (int mf = 0; mf < 2; ++mf)
#pragma unroll
    for (int ks = 0; ks < 8; ++ks)
      qreg[mf][ks] = *(const bf16x8*)(qb + (size_t)(qrow + mf * 16) * 768 +
                                      ks * 32 + quad * 8);

  f32x4 oacc[2][4];
#pragma unroll
  for (int mi = 0; mi < 2; ++mi)
#pragma unroll
    for (int ni = 0; ni < 4; ++ni) oacc[mi][ni] = (f32x4)(0.0f);
  float rs[2][4] = {};

  __syncthreads();  // drain tile-0 K/V DMAs + qreg loads
  __builtin_amdgcn_sched_barrier(0);

  const bf16* pKr = Ks + (wn * 16 + m15) * 64 + fq * 8;
  const bf16* pVr = Vs + wn * 4096 + m15 * 64 + fq * 8;
  // P write: row r = wm*32 + mf*16 + quad*4 + i, col k = wn*16 + m15;
  // granule p = (k>>3) ^ (2*((r>>2)&3)) = gP ^ (quad<<1)  (wm,mf,i drop out)
  const int gP = wn * 2 + (m15 >> 3);
  bf16* pPw = Ps + (wm * 32 + quad * 4) * 64 + ((gP ^ (quad << 1)) << 3) +
              (m15 & 7);
  // P read: row r = wm*32 + m15 + mi*16 -> (r>>2)&3 = (m15>>2)&3
  const int xr = ((m15 >> 2) & 3) << 1;
  const bf16* pPr = Ps + (wm * 32 + m15) * 64;

  for (int t = 0; t < 16; ++t) {
    // ---- S phase: sacc[mf] = Q @ K^T, wave tile 32 rows x 16 keys
    f32x4 sacc[2];
#pragma unroll
    for (int mf = 0; mf < 2; ++mf) sacc[mf] = (f32x4)(0.0f);
#pragma unroll
    for (int ks = 0; ks < 8; ++ks) {
      const bf16x8 bvk =
          *(const bf16x8*)(pKr + (ks >> 1) * 4096 + (ks & 1) * 32);
#pragma unroll
      for (int mf = 0; mf < 2; ++mf)
        sacc[mf] = __builtin_amdgcn_mfma_f32_16x16x32_bf16(qreg[mf][ks], bvk,
                                                           sacc[mf], 0, 0, 0);
    }
    // ---- exp + P write (swizzled, conflict-free) + row-sum accumulate
#pragma unroll
    for (int mf = 0; mf < 2; ++mf)
#pragma unroll
      for (int i = 0; i < 4; ++i) {
        const float pe = exp2f(sacc[mf][i] * 0.09016844136f);  // /16 * log2 e
        rs[mf][i] += pe;
        pPw[mf * 1024 + i * 64] = __float2bfloat16(pe);
      }
    __builtin_amdgcn_sched_barrier(0);
    __syncthreads();  // mid: Ps visible; Ks(t) dead; V(t) DMA long drained
    __builtin_amdgcn_sched_barrier(0);
    if (t < 15) STAGE_K(t + 1);  // drains at end barrier, hidden under PV
    // ---- PV: oacc += P @ V ; wave tile 32 rows x 64 d
#pragma unroll
    for (int sub = 0; sub < 2; ++sub) {
      bf16x8 pa[2], bvv[4];
#pragma unroll
      for (int mi = 0; mi < 2; ++mi)
        pa[mi] = *(const bf16x8*)(pPr + mi * 1024 +
                                  ((((sub << 2) | quad) ^ xr) << 3));
#pragma unroll
      for (int ni = 0; ni < 4; ++ni)
        bvv[ni] = *(const bf16x8*)(pVr + ni * 1024 + sub * 32);
#pragma unroll
      for (int mi = 0; mi < 2; ++mi)
#pragma unroll
        for (int ni = 0; ni < 4; ++ni)
          oacc[mi][ni] = __builtin_amdgcn_mfma_f32_16x16x32_bf16(
              pa[mi], bvv[ni], oacc[mi][ni], 0, 0, 0);
    }
    __builtin_amdgcn_sched_barrier(0);
    __syncthreads();  // end: Vs(t)+Ps dead; K(t+1) DMA drained here
    __builtin_amdgcn_sched_barrier(0);
    if (t < 15) STAGE_V(t + 1);  // drains at next mid barrier, hidden under S
  }
#undef STAGE_K
#undef STAGE_V

  // ---- epilogue: O partials (bf16) + lpart channel (b*16 + sp*4 + wn)
  const int crow0 = bx * 64 + wm * 32 + quad * 4;
  const int ccol0 = wn * 64 + m15;
#pragma unroll
  for (int mi = 0; mi < 2; ++mi)
#pragma unroll
    for (int ni = 0; ni < 4; ++ni)
#pragma unroll
      for (int i = 0; i < 4; ++i)
        attp[(size_t)(crow0 + mi * 16 + i) * 256 + ccol0 + ni * 16] =
            __float2bfloat16(oacc[mi][ni][i]);
  float* lp = lpart + (size_t)v * 131072 +
              (size_t)(b * 16 + sp * 4 + wn) * 4096 + bx * 64 + wm * 32;
#pragma unroll
  for (int mf = 0; mf < 2; ++mf)
#pragma unroll
    for (int i = 0; i < 4; ++i) {
      float sv = rs[mf][i];
      sv += __shfl_xor(sv, 1);
      sv += __shfl_xor(sv, 2);
      sv += __shfl_xor(sv, 4);
      sv += __shfl_xor(sv, 8);
      if (m15 == 0) lp[mf * 16 + quad * 4 + i] = sv;
    }
}

// ---------------------------------------------------------------------------
// residual + LayerNorm from split-K PV partials and lpart row sums.
// PT = partial dtype: bf16 (fused) / float (fallback). nch lpart channels.
// FUSE=true : emit 9 bf16 KAN basis channels directly (no x buffer).
// ---------------------------------------------------------------------------
template <bool FUSE, typename PT>
__global__ __launch_bounds__(256) void resid_ln_kernel(
    const PT* __restrict__ attp, const float* __restrict__ lpart,
    const float* __restrict__ tok, const float* __restrict__ gamma,
    const float* __restrict__ beta, float* __restrict__ xout,
    bf16* __restrict__ basis, int nch, int vIdx) {
  __shared__ float red[4];
  __shared__ float sinvl;
  __shared__ __align__(16) bf16 st[2304];  // 256 elems x 9 channels
  const int n = (int)blockIdx.x;  // 0..8191 ; b = n>>12
  const int d = (int)threadIdx.x;
  const int b = n >> 12, r = n & 4095;
  float ls = 0.f;
  if (d < nch) ls = lpart[((size_t)(b * nch + d)) * 4096 + r];
  ls = wave_sum(ls);
  if (d == 0) sinvl = 1.0f / ls;
  const size_t abase = (size_t)(b * 4) * 1048576 + (size_t)r * 256 + d;
  const float asum = to_f32(attp[abase]) + to_f32(attp[abase + 1048576]) +
                     to_f32(attp[abase + 2097152]) +
                     to_f32(attp[abase + 3145728]);
  __syncthreads();
  const float y = asum * sinvl + tok[(size_t)n * 256 + d];
  float s = wave_sum(y);
  if ((d & 63) == 0) red[d >> 6] = s;
  __syncthreads();
  const float mu = (red[0] + red[1] + red[2] + red[3]) * (1.0f / 256.0f);
  __syncthreads();
  const float c = y - mu;
  float s2 = wave_sum(c * c);
  if ((d & 63) == 0) red[d >> 6] = s2;
  __syncthreads();
  const float var = (red[0] + red[1] + red[2] + red[3]) * (1.0f / 256.0f);
  const float rstd = rsqrtf(var + 1e-5f);
  const float val = c * rstd * gamma[d] + beta[d];
  if constexpr (!FUSE) {
    xout[(size_t)n * 768 + vIdx * 256 + d] = val;
  } else {
#pragma unroll
    for (int f = 0; f < 8; ++f)
      st[d * 9 + f] = __float2bfloat16(b3_cardinal(val, 5.5f - (float)f));
    st[d * 9 + 8] = __float2bfloat16(val / (1.0f + __expf(-val)));
    __syncthreads();
    float4* gb = (float4*)((char*)basis + (size_t)n * 13824 + vIdx * 4608);
    const float4* sb = (const float4*)st;
    gb[d] = sb[d];
    if (d < 32) gb[256 + d] = sb[256 + d];
  }
}

// ---------------------------------------------------------------------------
__global__ __launch_bounds__(256) void prep_w(
    const float* __restrict__ bw, const float* __restrict__ sw,
    const float* __restrict__ scaler, bf16* __restrict__ Wmat) {
  const int o = blockIdx.x;
  for (int ii = 0; ii < 3; ++ii) {
    const int i = ii * 256 + (int)threadIdx.x;
    const float s = scaler[(size_t)o * 768 + i];
    bf16* p = Wmat + (size_t)o * 6912 + i * 9;
    const float* swp = sw + ((size_t)o * 768 + i) * 8;
#pragma unroll
    for (int f = 0; f < 8; ++f) p[f] = __float2bfloat16(swp[f] * s);
    p[8] = __float2bfloat16(bw[(size_t)o * 768 + i]);
  }
}

__global__ __launch_bounds__(256) void prep_qkvw(
    const float* __restrict__ wq, const float* __restrict__ wk,
    const float* __restrict__ wv, const float* __restrict__ bq,
    const float* __restrict__ bk, const float* __restrict__ bv,
    bf16* __restrict__ wqkvb, float* __restrict__ bqkv) {
  const int idx = blockIdx.x * 256 + (int)threadIdx.x;
  const int row = idx >> 8, col = idx & 255;
  const float* src = row < 256 ? wq : (row < 512 ? wk : wv);
  wqkvb[idx] = __float2bfloat16(src[((row & 255) << 8) + col]);
  if (idx < 768)
    bqkv[idx] = idx < 256 ? bq[idx] : (idx < 512 ? bk[idx - 256] : bv[idx - 512]);
}

__global__ __launch_bounds__(256) void cast_tok3(
    const float4* __restrict__ t0, const float4* __restrict__ t1,
    const float4* __restrict__ t2, bf16* __restrict__ dst) {
  const int vv = blockIdx.y;
  const float4* src = vv == 0 ? t0 : (vv == 1 ? t1 : t2);
  const int idx = blockIdx.x * 256 + (int)threadIdx.x;
  const float4 val = src[idx];
  bf16* p = dst + (size_t)vv * 2097152 + (size_t)idx * 4;
  p[0] = __float2bfloat16(val.x);
  p[1] = __float2bfloat16(val.y);
  p[2] = __float2bfloat16(val.z);
  p[3] = __float2bfloat16(val.w);
}

// vT[z][d][s] = qkv[z*4096+s][512+d]
__global__ __launch_bounds__(256) void transpose_v(
    const bf16* __restrict__ qkv, bf16* __restrict__ vT) {
  __shared__ bf16 tle[64][65];
  const int s0 = blockIdx.x << 6, d0 = blockIdx.y << 6, z = blockIdx.z;
  const int tid = (int)threadIdx.x;
  const int c = tid & 63, rr = tid >> 6;
  for (int r = 0; r < 64; r += 4)
    tle[r + rr][c] = qkv[(size_t)(z * 4096 + s0 + r + rr) * 768 + 512 + d0 + c];
  __syncthreads();
  for (int r = 0; r < 64; r += 4)
    vT[(size_t)z * 1048576 + (size_t)(d0 + r + rr) * 4096 + s0 + c] =
        tle[c][r + rr];
}

// ---------------------------------------------------------------------------
// fallback basis: basis[n][i*9+f] from x (Cox-de-Boor, proven R6)
// ---------------------------------------------------------------------------
__global__ __launch_bounds__(256) void basis_kernel(
    const float* __restrict__ x, bf16* __restrict__ basis) {
  const int i = blockIdx.x * 256 + (int)threadIdx.x;  // 0..767
  const int n = blockIdx.y;
  const float xv = x[(size_t)n * 768 + i];
  float b[11];
#pragma unroll
  for (int m = 0; m < 11; ++m) {
    const float g0 = 0.4f * (float)(m - 3) - 1.0f;
    const float g1 = 0.4f * (float)(m - 2) - 1.0f;
    b[m] = (xv >= g0 && xv < g1) ? 1.0f : 0.0f;
  }
#pragma unroll
  for (int k = 1; k <= 3; ++k) {
    const float inv = 1.0f / (0.4f * (float)k);
#pragma unroll
    for (int m = 0; m + k < 11; ++m) {
      const float gm = 0.4f * (float)(m - 3) - 1.0f;
      const float gmk1 = 0.4f * (float)(m + k - 2) - 1.0f;
      b[m] = (xv - gm) * inv * b[m] + (gmk1 - xv) * inv * b[m + 1];
    }
  }
  bf16* p = basis + (size_t)n * 6912 + i * 9;
#pragma unroll
  for (int f = 0; f < 8; ++f) p[f] = __float2bfloat16(b[f]);
  p[8] = __float2bfloat16(xv / (1.0f + __expf(-xv)));
}

__global__ __launch_bounds__(256) void combine4_kernel(
    const float4* __restrict__ p, float4* __restrict__ out) {
  const int idx = blockIdx.x * 256 + (int)threadIdx.x;
  const float4 a = p[idx];
  const float4 b = p[idx + 524288];
  const float4 c = p[idx + 1048576];
  const float4 d = p[idx + 1572864];
  out[idx] =
      make_float4(a.x + b.x + c.x + d.x, a.y + b.y + c.y + d.y,
                  a.z + b.z + c.z + d.z, a.w + b.w + c.w + d.w);
}

__global__ __launch_bounds__(256) void combine6_kernel(
    const float4* __restrict__ p, float4* __restrict__ out) {
  const int idx = blockIdx.x * 256 + (int)threadIdx.x;
  float4 s = p[idx];
#pragma unroll
  for (int j = 1; j < 6; ++j) {
    const float4 a = p[idx + (size_t)j * 524288];
    s.x += a.x;
    s.y += a.y;
    s.z += a.z;
    s.w += a.w;
  }
  out[idx] = s;
}

// ---------------------------------------------------------------------------
extern "C" void kernel_launch(void* const* d_in, const int* in_sizes, int n_in,
                              void* d_out, int out_size, void* d_ws,
                              size_t ws_size, hipStream_t stream) {
  const float* tok[3] = {(const float*)d_in[0], (const float*)d_in[1],
                         (const float*)d_in[2]};
  const float* wq = (const float*)d_in[3];
  const float* bq = (const float*)d_in[4];
  const float* wk = (const float*)d_in[5];
  const float* bk = (const float*)d_in[6];
  const float* wv = (const float*)d_in[7];
  const float* bv = (const float*)d_in[8];
  // d_in[9] view_emb unused (softmax-invariant)
  const float* lng[3] = {(const float*)d_in[10], (const float*)d_in[12],
                         (const float*)d_in[14]};
  const float* lnb[3] = {(const float*)d_in[11], (const float*)d_in[13],
                         (const float*)d_in[15]};
  const float* bw = (const float*)d_in[16];
  const float* sw = (const float*)d_in[17];
  const float* scaler = (const float*)d_in[18];

  // fused layout (R13, total 169,085,952 B <= known-safe 194,776,064):
  //   basis @0 (113,246,208) -- written by resid_ln AFTER attention; until
  //     then sub-aliased: tokb @0 (12.58M) | qkv @12,582,912 (37.75M) |
  //     vT @50,331,648 (12.58M, ends 62,914,560)
  //   attb (bf16 partials, 24 x 2,097,152 B) @113,246,208 -> 163,577,856
  //   lpart_f @163,577,856 (1.57M) -> 165,150,720
  //   Wmat @165,150,720 (3.54M) | wqkvb @168,689,664 | bqkv @169,082,880
  //   pout (KAN z=6, 50,331,648 B fp32) aliases attb (dead after resid_ln)
  // fallback (unchanged): Pb @62,914,560 | lpart @130,023,424 |
  //   attp @132,120,576 | x @165,675,008 | basis aliases [0,..) |
  //   Wmat @190,840,832 | pout aliases attp.
  const bool fused = ws_size >= 169085952ull;
  char* w8 = (char*)d_ws;
  bf16* tokb = (bf16*)(w8 + 0);
  bf16* qkv = (bf16*)(w8 + 12582912);
  bf16* vT = (bf16*)(w8 + 50331648);
  float* x;
  bf16* basis;
  bf16* Wmat;
  float* pout;
  // fallback pointers
  bf16* Pb = (bf16*)(w8 + 62914560);
  float* lpart = (float*)(w8 + 130023424);
  float* attp = (float*)(w8 + 132120576);
  // fused pointers
  bf16* attb = (bf16*)(w8 + 113246208);
  float* lpart_f = (float*)(w8 + 163577856);
  if (fused) {
    x = nullptr;
    basis = (bf16*)(w8 + 0);
    Wmat = (bf16*)(w8 + 165150720);
    pout = (float*)(w8 + 113246208);  // attb dead after resid_ln
  } else {
    x = (float*)(w8 + 165675008);
    basis = (bf16*)(w8 + 0);
    Wmat = (bf16*)(w8 + 190840832);
    pout = attp;  // 4 x 8.39 MB, attp dead
  }
  bf16* wqkvb = (bf16*)((char*)Wmat + 3538944);
  float* bqkv = (float*)((char*)wqkvb + 393216);

  prep_w<<<256, 256, 0, stream>>>(bw, sw, scaler, Wmat);
  prep_qkvw<<<768, 256, 0, stream>>>(wq, wk, wv, bq, bk, bv, wqkvb, bqkv);
  cast_tok3<<<dim3(2048, 3), 256, 0, stream>>>(
      (const float4*)tok[0], (const float4*)tok[1], (const float4*)tok[2],
      tokb);

  // QKV all views: [24576,256] @ [768,256]^T + bias -> qkv bf16
  mfma_gemm_bt<bf16, false><<<dim3(6, 192, 1), 256, 0, stream>>>(
      tokb, wqkvb, bqkv, qkv, nullptr, 256, 256, 256, 768, 1, 0, 0, 0, 0, 0,
      0, 1.0f);
  transpose_v<<<dim3(64, 4, 6), 256, 0, stream>>>(qkv, vT);

  if (fused) {
    // fused flash attention: all views/batches/splits in one dispatch
    fused_attn<<<dim3(64, 24), 512, 0, stream>>>(qkv, vT, attb, lpart_f);
    for (int v = 0; v < 3; ++v)
      resid_ln_kernel<true, bf16><<<8192, 256, 0, stream>>>(
          attb + (size_t)v * 8388608, lpart_f + (size_t)v * 131072, tok[v],
          lng[v], lnb[v], nullptr, basis, 16, v);
    // KAN split-K=6 (z=6, 768 blocks = 3/CU): slice K=1152
    mfma_gemm_bt<float, false><<<dim3(2, 64, 6), 256, 0, stream>>>(
        basis, Wmat, nullptr, pout, nullptr, 1152, 6912, 6912, 256, 3, 0,
        1152, 0, 1152, 2097152, 0, 1.0f);
    combine6_kernel<<<2048, 256, 0, stream>>>((const float4*)pout,
                                              (float4*)d_out);
  } else {
    for (int v = 0; v < 3; ++v) {
      const bf16* qb = qkv + (size_t)(2 * v) * 4096 * 768;
      // scores both batches (z=2): P = exp(q@k^T/16) bf16 + lpart partials
      mfma_gemm_bt<bf16, true><<<dim3(32, 32, 2), 256, 0, stream>>>(
          qb, qb + 256, nullptr, Pb, lpart, 256, 768, 768, 4096, 1, 0,
          3145728, 0, 3145728, 16777216, 262144, 0.0625f);
      // PV split-K=4 x batch (z=8): attp[z] = P-slice @ vT-slice^T
      mfma_gemm_bt<float, false><<<dim3(2, 32, 8), 256, 0, stream>>>(
          Pb, vT + (size_t)(2 * v) * 1048576, nullptr, attp, nullptr, 1024,
          4096, 4096, 256, 2, 16777216, 1024, 1048576, 1024, 1048576, 0, 1.0f);
      resid_ln_kernel<false, float><<<8192, 256, 0, stream>>>(
          attp, lpart, tok[v], lng[v], lnb[v], x, nullptr, 64, v);
    }
    basis_kernel<<<dim3(3, 8192), 256, 0, stream>>>(x, basis);
    mfma_gemm_bt<float, false><<<dim3(2, 64, 4), 256, 0, stream>>>(
        basis, Wmat, nullptr, pout, nullptr, 1728, 6912, 6912, 256, 2, 0,
        1728, 0, 1728, 2097152, 0, 1.0f);
    combine4_kernel<<<2048, 256, 0, stream>>>((const float4*)pout,
                                              (float4*)d_out);
  }
}

// Round 12
// 415.022 us; speedup vs baseline: 1.0749x; 1.0722x over previous
//
#include <hip/hip_runtime.h>
#include <hip/hip_bf16.h>
#include <math.h>

// ---------------------------------------------------------------------------
// B=2, S=4096, D=256, IN=768, N_BASIS=8, spline grid h=0.4
// view_emb adds a row-constant to pre-softmax scores -> cancelled -> unused.
// Softmax without max-subtraction: |q.k|/16 <= ~1.7 -> exp in [0.2,5.5] ->
// online softmax is LINEAR: O = sum exp(s)v, l = sum exp(s).
// R22: resubmission of R21 — two consecutive "container failed twice" errors
// with NO pytest/timing output (vs R0's kernel failure which returned full
// diagnostics) => infra-side flake, not kernel-side. Source re-audited:
// prep_all partitions in-bounds, ATOMIC GEMM addressing exact, zero_out
// covers d_out exactly, fused_attn byte-identical to the R17 398.9us build.
// Structure: fused_attn = EXACT R17 (174.6us proven config); KAN split-K
// accumulates via atomicAdd into zeroed d_out (deletes pout 50MB write +
// combine6 58MB round-trip + 1 dispatch); prep_w/prep_qkvw/cast_tok3 merged
// into one prep_all dispatch. fp32 atomic order noise ~1e-5 << 0.0497.
// R13: fused layout 169.1MB; attp partials bf16. R11: sched_barrier pins.
// ---------------------------------------------------------------------------

typedef __hip_bfloat16 bf16;
using bf16x8 = __attribute__((ext_vector_type(8))) __bf16;
using f32x4  = __attribute__((ext_vector_type(4))) float;

__device__ __forceinline__ void load_lds16(const void* g, void* l) {
  __builtin_amdgcn_global_load_lds((__attribute__((address_space(1))) void*)g,
                                   (__attribute__((address_space(3))) void*)l,
                                   16, 0, 0);
}

__device__ __forceinline__ float wave_sum(float v) {
#pragma unroll
  for (int o = 32; o > 0; o >>= 1) v += __shfl_down(v, o, 64);
  return v;
}

__device__ __forceinline__ float to_f32(float v) { return v; }
__device__ __forceinline__ float to_f32(bf16 v) { return __bfloat162float(v); }

// closed-form cardinal cubic B-spline segment (validated R7)
__device__ __forceinline__ float b3_cardinal(float x, float tofs) {
  const float t = fmaf(x, 2.5f, tofs);
  const float tc = fminf(fmaxf(t, 0.0f), 4.0f);
  const float p2 = fmaxf(tc - 1.0f, 0.0f);
  const float p3 = fmaxf(tc - 2.0f, 0.0f);
  const float p4 = fmaxf(tc - 3.0f, 0.0f);
  return (tc * tc * tc - 4.0f * p2 * p2 * p2 + 6.0f * p3 * p3 * p3 -
          4.0f * p4 * p4 * p4) * (1.0f / 6.0f);
}

// ---------------------------------------------------------------------------
// bf16 MFMA GEMM, BT form, BK=64 (proven): used by QKV + KAN (+ fallback).
// ATOMIC=true: epilogue atomicAdd into C (split-K accumulation, zC=0).
// ---------------------------------------------------------------------------
template <typename OutT, bool EXP, bool ATOMIC = false>
__global__ __launch_bounds__(256) void mfma_gemm_bt(
    const bf16* __restrict__ A, const bf16* __restrict__ B,
    const float* __restrict__ bias, OutT* __restrict__ C,
    float* __restrict__ lpart, int K, int lda, int ldb, int ldc, int zshift,
    size_t zAh, size_t zAl, size_t zBh, size_t zBl, size_t zC, size_t zL,
    float scale) {
  __shared__ __align__(16) bf16 As[8192];  // 128 x 64
  __shared__ __align__(16) bf16 Bs[8192];
  const int tid = (int)threadIdx.x;
  const int lane = tid & 63;
  const int w = tid >> 6;
  const int m0 = (int)blockIdx.y << 7;
  const int n0 = (int)blockIdx.x << 7;
  const size_t z = blockIdx.z;
  const size_t zlo = z & (((size_t)1 << zshift) - 1);
  A += (z >> zshift) * zAh + zlo * zAl;
  B += (z >> zshift) * zBh + zlo * zBl;
  C += z * zC;
  if (EXP) lpart += z * zL;

  // staging geometry
  const int srow8 = lane >> 3;  // row within 8-row chunk
  const int g8 = (lane & 4) | ((lane & 3) ^ ((lane >> 4) & 3));
  const bf16* gA[4];
  const bf16* gB[4];
  bf16* lA[4];
  bf16* lB[4];
#pragma unroll
  for (int j = 0; j < 4; ++j) {
    const int c = w + 4 * j;
    gA[j] = A + (size_t)(m0 + c * 8 + srow8) * lda + g8 * 8;
    gB[j] = B + (size_t)(n0 + c * 8 + srow8) * ldb + g8 * 8;
    lA[j] = As + c * 512;
    lB[j] = Bs + c * 512;
  }

  // fragment geometry
  const int m15 = lane & 15, quad = lane >> 4;
  const int fq = quad ^ ((m15 >> 1) & 3);
  const bf16* pA = As + (size_t)(((w >> 1) << 6) + m15) * 64 + fq * 8;
  const bf16* pB = Bs + (size_t)(((w & 1) << 6) + m15) * 64 + fq * 8;

  f32x4 acc[4][4];
#pragma unroll
  for (int mi = 0; mi < 4; ++mi)
#pragma unroll
    for (int ni = 0; ni < 4; ++ni) acc[mi][ni] = (f32x4)(0.0f);

  for (int k0 = 0; k0 < K; k0 += 64) {
#pragma unroll
    for (int j = 0; j < 4; ++j) {
      load_lds16(gA[j], lA[j]);
      load_lds16(gB[j], lB[j]);
      gA[j] += 64;
      gB[j] += 64;
    }
    __syncthreads();
    __builtin_amdgcn_sched_barrier(0);  // ds_reads must not hoist above barrier
    bf16x8 av[4][2], bv[4][2];
#pragma unroll
    for (int mi = 0; mi < 4; ++mi)
#pragma unroll
      for (int sub = 0; sub < 2; ++sub) {
        av[mi][sub] = *(const bf16x8*)(pA + mi * 1024 + sub * 32);
        bv[mi][sub] = *(const bf16x8*)(pB + mi * 1024 + sub * 32);
      }
#pragma unroll
    for (int sub = 0; sub < 2; ++sub)
#pragma unroll
      for (int mi = 0; mi < 4; ++mi)
#pragma unroll
        for (int ni = 0; ni < 4; ++ni)
          acc[mi][ni] = __builtin_amdgcn_mfma_f32_16x16x32_bf16(
              av[mi][sub], bv[ni][sub], acc[mi][ni], 0, 0, 0);
    __builtin_amdgcn_sched_barrier(0);  // reads/MFMAs must not sink below
    __syncthreads();
    __builtin_amdgcn_sched_barrier(0);  // next-iter LDS-DMA must not hoist
  }

  const int crow = m0 + ((w >> 1) << 6) + quad * 4;
  const int ccol = n0 + ((w & 1) << 6) + m15;
  float rs[4][4] = {};
#pragma unroll
  for (int ni = 0; ni < 4; ++ni) {
    const int col = ccol + ni * 16;
    const float bb = bias ? bias[col] : 0.0f;
#pragma unroll
    for (int mi = 0; mi < 4; ++mi) {
#pragma unroll
      for (int i = 0; i < 4; ++i) {
        const int row = crow + mi * 16 + i;
        float v = acc[mi][ni][i] * scale + bb;
        if constexpr (EXP) {
          v = __expf(v);
          rs[mi][i] += v;
        }
        if constexpr (sizeof(OutT) == 2)
          C[(size_t)row * ldc + col] = __float2bfloat16(v);
        else if constexpr (ATOMIC)
          atomicAdd((float*)&C[(size_t)row * ldc + col], v);
        else
          C[(size_t)row * ldc + col] = v;
      }
    }
  }
  if constexpr (EXP) {
    const int ch = ((int)blockIdx.x << 1) | (w & 1);
#pragma unroll
    for (int mi = 0; mi < 4; ++mi)
#pragma unroll
      for (int i = 0; i < 4; ++i) {
        float sv = rs[mi][i];
        sv += __shfl_xor(sv, 1);
        sv += __shfl_xor(sv, 2);
        sv += __shfl_xor(sv, 4);
        sv += __shfl_xor(sv, 8);
        if (m15 == 0)
          lpart[(size_t)ch * 4096 + crow + mi * 16 + i] = sv;
      }
  }
}

// ---------------------------------------------------------------------------
// fused flash attention — EXACT R17 configuration (measured 174.6us):
// Block: 512 thr = 8 waves (2 wm x 4 wn). Q-tile 128 rows, split of 1024
// keys = 16 tiles x 64 keys. grid = (32 Qtiles, 24 = v*8 + b*4 + sp).
// LDS 80KB (Ks 32K + Vs 32K + Ps 16K), launch_bounds(512,2) -> VGPR 128.
// Single K/V buffers; K(t+1) staged after mid barrier (drain hidden under
// PV), V(t+1) staged after end barrier (drain hidden under next S). Ps
// [128][64] granule swizzle p=(k>>3)^(2*((r>>2)&3)): conflict-free r/w.
// Outputs: attp bf16 partials + lpart 16 ch/(batch,view).
// ---------------------------------------------------------------------------
__global__ __launch_bounds__(512, 2) void fused_attn(
    const bf16* __restrict__ qkv, const bf16* __restrict__ vT,
    bf16* __restrict__ attp, float* __restrict__ lpart) {
  __shared__ __align__(16) bf16 Ks[16384];  // 4 subtiles 64(keys)x64(k)
  __shared__ __align__(16) bf16 Vs[16384];  // 4 rowgroups 64(d)x64(key)
  __shared__ __align__(16) bf16 Ps[8192];   // 128 x 64, granule-swizzled
  const int tid = (int)threadIdx.x;
  const int lane = tid & 63;
  const int w = tid >> 6;   // 0..7
  const int wm = w >> 2;    // 0..1 : Q-row half
  const int wn = w & 3;     // 0..3 : S key-16-col / O d-64-col
  const int bx = (int)blockIdx.x;           // Q-tile
  const int by = (int)blockIdx.y;           // v*8 + b*4 + sp
  const int v = by >> 3, b = (by >> 2) & 1, sp = by & 3;
  const bf16* qb = qkv + (size_t)((v * 2 + b) * 4096) * 768;
  const bf16* vb = vT + (size_t)(v * 2 + b) * 1048576;
  attp += (size_t)by * 1048576;

  const int srow8 = lane >> 3;
  const int g8 = (lane & 4) | ((lane & 3) ^ ((lane >> 4) & 3));
  const int m15 = lane & 15, quad = lane >> 4;
  const int fq = quad ^ ((m15 >> 1) & 3);
  const int key0 = sp * 1024;

  // staging bases (chunk c = w of each 64x64 subtile)
  const bf16* gKb = qb + (size_t)(key0 + w * 8 + srow8) * 768 + 256 + g8 * 8;
  const bf16* gVb = vb + (size_t)(w * 8 + srow8) * 4096 + key0 + g8 * 8;

#define STAGE_K(T)                                               \
  do {                                                           \
    const bf16* gk_ = gKb + (size_t)(T) * 49152;                 \
    bf16* lk_ = Ks + w * 512;                                    \
    _Pragma("unroll") for (int j_ = 0; j_ < 4; ++j_)             \
        load_lds16(gk_ + j_ * 64, lk_ + j_ * 4096);              \
  } while (0)
#define STAGE_V(T)                                               \
  do {                                                           \
    const bf16* gv_ = gVb + (T) * 64;                            \
    bf16* lv_ = Vs + w * 512;                                    \
    _Pragma("unroll") for (int j_ = 0; j_ < 4; ++j_)             \
        load_lds16(gv_ + (size_t)j_ * 262144, lv_ + j_ * 4096);  \
  } while (0)

  STAGE_K(0);
  STAGE_V(0);

  // full Q fragments (compiler keeps/remats under the 128-VGPR cap;
  // re-loads are L1/L2 hits)
  bf16x8 qreg[4][8];
  const int qrow = bx * 128 + wm * 64 + m15;
#pragma unroll
  for (int mf = 0; mf < 4; ++mf)
#pragma unroll
    for (int ks = 0; ks < 8; ++ks)
      qreg[mf][ks] = *(const bf16x8*)(qb + (size_t)(qrow + mf * 16) * 768 +
                                      ks * 32 + quad * 8);

  f32x4 oacc[4][4];
#pragma unroll
  for (int mi = 0; mi < 4; ++mi)
#pragma unroll
    for (int ni = 0; ni < 4; ++ni) oacc[mi][ni] = (f32x4)(0.0f);
  float rs[4][4] = {};

  __syncthreads();  // drain tile-0 K/V DMAs + qreg loads
  __builtin_amdgcn_sched_barrier(0);

  const bf16* pKr = Ks + (wn * 16 + m15) * 64 + fq * 8;
  const bf16* pVr = Vs + wn * 4096 + m15 * 64 + fq * 8;
  // P write: row r = wm*64 + mf*16 + quad*4 + i, col k = wn*16 + m15;
  // granule p = (k>>3) ^ (2*((r>>2)&3)) = gP ^ (quad<<1)  (mf,i drop out)
  const int gP = wn * 2 + (m15 >> 3);
  bf16* pPw = Ps + (wm * 64 + quad * 4) * 64 + ((gP ^ (quad << 1)) << 3) +
              (m15 & 7);
  // P read: row r = wm*64 + m15 + mi*16 -> (r>>2)&3 = (m15>>2)&3
  const int xr = ((m15 >> 2) & 3) << 1;
  const bf16* pPr = Ps + (wm * 64 + m15) * 64;

  for (int t = 0; t < 16; ++t) {
    // ---- S phase: sacc[mf] = Q @ K^T, wave tile 64 rows x 16 keys
    f32x4 sacc[4];
#pragma unroll
    for (int mf = 0; mf < 4; ++mf) sacc[mf] = (f32x4)(0.0f);
#pragma unroll
    for (int ks = 0; ks < 8; ++ks) {
      const bf16x8 bvk =
          *(const bf16x8*)(pKr + (ks >> 1) * 4096 + (ks & 1) * 32);
#pragma unroll
      for (int mf = 0; mf < 4; ++mf)
        sacc[mf] = __builtin_amdgcn_mfma_f32_16x16x32_bf16(qreg[mf][ks], bvk,
                                                           sacc[mf], 0, 0, 0);
    }
    // ---- exp + P write (swizzled, conflict-free) + row-sum accumulate
#pragma unroll
    for (int mf = 0; mf < 4; ++mf)
#pragma unroll
      for (int i = 0; i < 4; ++i) {
        const float pe = exp2f(sacc[mf][i] * 0.09016844136f);  // /16 * log2 e
        rs[mf][i] += pe;
        pPw[mf * 1024 + i * 64] = __float2bfloat16(pe);
      }
    __builtin_amdgcn_sched_barrier(0);
    __syncthreads();  // mid: Ps visible; Ks(t) dead; V(t) DMA long drained
    __builtin_amdgcn_sched_barrier(0);
    if (t < 15) STAGE_K(t + 1);  // drains at end barrier, hidden under PV
    // ---- PV: oacc += P @ V ; wave tile 64 rows x 64 d
#pragma unroll
    for (int sub = 0; sub < 2; ++sub) {
      bf16x8 pa[4], bvv[4];
#pragma unroll
      for (int mi = 0; mi < 4; ++mi)
        pa[mi] = *(const bf16x8*)(pPr + mi * 1024 +
                                  ((((sub << 2) | quad) ^ xr) << 3));
#pragma unroll
      for (int ni = 0; ni < 4; ++ni)
        bvv[ni] = *(const bf16x8*)(pVr + ni * 1024 + sub * 32);
#pragma unroll
      for (int mi = 0; mi < 4; ++mi)
#pragma unroll
        for (int ni = 0; ni < 4; ++ni)
          oacc[mi][ni] = __builtin_amdgcn_mfma_f32_16x16x32_bf16(
              pa[mi], bvv[ni], oacc[mi][ni], 0, 0, 0);
    }
    __builtin_amdgcn_sched_barrier(0);
    __syncthreads();  // end: Vs(t)+Ps dead; K(t+1) DMA drained here
    __builtin_amdgcn_sched_barrier(0);
    if (t < 15) STAGE_V(t + 1);  // drains at next mid barrier, hidden under S
  }
#undef STAGE_K
#undef STAGE_V

  // ---- epilogue: O partials (bf16) + lpart channel (b*16 + sp*4 + wn)
  const int crow0 = bx * 128 + wm * 64 + quad * 4;
  const int ccol0 = wn * 64 + m15;
#pragma unroll
  for (int mi = 0; mi < 4; ++mi)
#pragma unroll
    for (int ni = 0; ni < 4; ++ni)
#pragma unroll
      for (int i = 0; i < 4; ++i)
        attp[(size_t)(crow0 + mi * 16 + i) * 256 + ccol0 + ni * 16] =
            __float2bfloat16(oacc[mi][ni][i]);
  float* lp = lpart + (size_t)v * 131072 +
              (size_t)(b * 16 + sp * 4 + wn) * 4096 + bx * 128 + wm * 64;
#pragma unroll
  for (int mf = 0; mf < 4; ++mf)
#pragma unroll
    for (int i = 0; i < 4; ++i) {
      float sv = rs[mf][i];
      sv += __shfl_xor(sv, 1);
      sv += __shfl_xor(sv, 2);
      sv += __shfl_xor(sv, 4);
      sv += __shfl_xor(sv, 8);
      if (m15 == 0) lp[mf * 16 + quad * 4 + i] = sv;
    }
}

// ---------------------------------------------------------------------------
// residual + LayerNorm from split-K PV partials and lpart row sums.
// PT = partial dtype: bf16 (fused) / float (fallback). nch lpart channels.
// FUSE=true : emit 9 bf16 KAN basis channels directly (no x buffer).
// ---------------------------------------------------------------------------
template <bool FUSE, typename PT>
__global__ __launch_bounds__(256) void resid_ln_kernel(
    const PT* __restrict__ attp, const float* __restrict__ lpart,
    const float* __restrict__ tok, const float* __restrict__ gamma,
    const float* __restrict__ beta, float* __restrict__ xout,
    bf16* __restrict__ basis, int nch, int vIdx) {
  __shared__ float red[4];
  __shared__ float sinvl;
  __shared__ __align__(16) bf16 st[2304];  // 256 elems x 9 channels
  const int n = (int)blockIdx.x;  // 0..8191 ; b = n>>12
  const int d = (int)threadIdx.x;
  const int b = n >> 12, r = n & 4095;
  float ls = 0.f;
  if (d < nch) ls = lpart[((size_t)(b * nch + d)) * 4096 + r];
  ls = wave_sum(ls);
  if (d == 0) sinvl = 1.0f / ls;
  const size_t abase = (size_t)(b * 4) * 1048576 + (size_t)r * 256 + d;
  const float asum = to_f32(attp[abase]) + to_f32(attp[abase + 1048576]) +
                     to_f32(attp[abase + 2097152]) +
                     to_f32(attp[abase + 3145728]);
  __syncthreads();
  const float y = asum * sinvl + tok[(size_t)n * 256 + d];
  float s = wave_sum(y);
  if ((d & 63) == 0) red[d >> 6] = s;
  __syncthreads();
  const float mu = (red[0] + red[1] + red[2] + red[3]) * (1.0f / 256.0f);
  __syncthreads();
  const float c = y - mu;
  float s2 = wave_sum(c * c);
  if ((d & 63) == 0) red[d >> 6] = s2;
  __syncthreads();
  const float var = (red[0] + red[1] + red[2] + red[3]) * (1.0f / 256.0f);
  const float rstd = rsqrtf(var + 1e-5f);
  const float val = c * rstd * gamma[d] + beta[d];
  if constexpr (!FUSE) {
    xout[(size_t)n * 768 + vIdx * 256 + d] = val;
  } else {
#pragma unroll
    for (int f = 0; f < 8; ++f)
      st[d * 9 + f] = __float2bfloat16(b3_cardinal(val, 5.5f - (float)f));
    st[d * 9 + 8] = __float2bfloat16(val / (1.0f + __expf(-val)));
    __syncthreads();
    float4* gb = (float4*)((char*)basis + (size_t)n * 13824 + vIdx * 4608);
    const float4* sb = (const float4*)st;
    gb[d] = sb[d];
    if (d < 32) gb[256 + d] = sb[256 + d];
  }
}

// ---------------------------------------------------------------------------
// merged prep: blocks 0..255 = prep_w ; 256..1023 = prep_qkvw ;
// 1024..7167 = cast_tok3 (2048 blocks per view).
// ---------------------------------------------------------------------------
__global__ __launch_bounds__(256) void prep_all(
    const float* __restrict__ bw, const float* __restrict__ sw,
    const float* __restrict__ scaler, bf16* __restrict__ Wmat,
    const float* __restrict__ wq, const float* __restrict__ wk,
    const float* __restrict__ wv, const float* __restrict__ bq,
    const float* __restrict__ bk, const float* __restrict__ bv,
    bf16* __restrict__ wqkvb, float* __restrict__ bqkv,
    const float4* __restrict__ t0, const float4* __restrict__ t1,
    const float4* __restrict__ t2, bf16* __restrict__ tokb) {
  const int bid = (int)blockIdx.x;
  const int tid = (int)threadIdx.x;
  if (bid < 256) {
    const int o = bid;
    for (int ii = 0; ii < 3; ++ii) {
      const int i = ii * 256 + tid;
      const float s = scaler[(size_t)o * 768 + i];
      bf16* p = Wmat + (size_t)o * 6912 + i * 9;
      const float* swp = sw + ((size_t)o * 768 + i) * 8;
#pragma unroll
      for (int f = 0; f < 8; ++f) p[f] = __float2bfloat16(swp[f] * s);
      p[8] = __float2bfloat16(bw[(size_t)o * 768 + i]);
    }
  } else if (bid < 1024) {
    const int idx = (bid - 256) * 256 + tid;
    const int row = idx >> 8, col = idx & 255;
    const float* src = row < 256 ? wq : (row < 512 ? wk : wv);
    wqkvb[idx] = __float2bfloat16(src[((row & 255) << 8) + col]);
    if (idx < 768)
      bqkv[idx] =
          idx < 256 ? bq[idx] : (idx < 512 ? bk[idx - 256] : bv[idx - 512]);
  } else {
    const int f = bid - 1024;
    const int vv = f >> 11;
    const int idx = (f & 2047) * 256 + tid;
    const float4* src = vv == 0 ? t0 : (vv == 1 ? t1 : t2);
    const float4 val = src[idx];
    bf16* p = tokb + (size_t)vv * 2097152 + (size_t)idx * 4;
    p[0] = __float2bfloat16(val.x);
    p[1] = __float2bfloat16(val.y);
    p[2] = __float2bfloat16(val.z);
    p[3] = __float2bfloat16(val.w);
  }
}

// zero d_out (8,388,608 B = 524288 float4) — replaces hipMemsetAsync
__global__ __launch_bounds__(256) void zero_out(float4* __restrict__ out) {
  const int idx = blockIdx.x * 256 + (int)threadIdx.x;
  out[idx] = make_float4(0.f, 0.f, 0.f, 0.f);
}

// vT[z][d][s] = qkv[z*4096+s][512+d]
__global__ __launch_bounds__(256) void transpose_v(
    const bf16* __restrict__ qkv, bf16* __restrict__ vT) {
  __shared__ bf16 tle[64][65];
  const int s0 = blockIdx.x << 6, d0 = blockIdx.y << 6, z = blockIdx.z;
  const int tid = (int)threadIdx.x;
  const int c = tid & 63, rr = tid >> 6;
  for (int r = 0; r < 64; r += 4)
    tle[r + rr][c] = qkv[(size_t)(z * 4096 + s0 + r + rr) * 768 + 512 + d0 + c];
  __syncthreads();
  for (int r = 0; r < 64; r += 4)
    vT[(size_t)z * 1048576 + (size_t)(d0 + r + rr) * 4096 + s0 + c] =
        tle[c][r + rr];
}

// ---------------------------------------------------------------------------
// fallback basis: basis[n][i*9+f] from x (Cox-de-Boor, proven R6)
// ---------------------------------------------------------------------------
__global__ __launch_bounds__(256) void basis_kernel(
    const float* __restrict__ x, bf16* __restrict__ basis) {
  const int i = blockIdx.x * 256 + (int)threadIdx.x;  // 0..767
  const int n = blockIdx.y;
  const float xv = x[(size_t)n * 768 + i];
  float b[11];
#pragma unroll
  for (int m = 0; m < 11; ++m) {
    const float g0 = 0.4f * (float)(m - 3) - 1.0f;
    const float g1 = 0.4f * (float)(m - 2) - 1.0f;
    b[m] = (xv >= g0 && xv < g1) ? 1.0f : 0.0f;
  }
#pragma unroll
  for (int k = 1; k <= 3; ++k) {
    const float inv = 1.0f / (0.4f * (float)k);
#pragma unroll
    for (int m = 0; m + k < 11; ++m) {
      const float gm = 0.4f * (float)(m - 3) - 1.0f;
      const float gmk1 = 0.4f * (float)(m + k - 2) - 1.0f;
      b[m] = (xv - gm) * inv * b[m] + (gmk1 - xv) * inv * b[m + 1];
    }
  }
  bf16* p = basis + (size_t)n * 6912 + i * 9;
#pragma unroll
  for (int f = 0; f < 8; ++f) p[f] = __float2bfloat16(b[f]);
  p[8] = __float2bfloat16(xv / (1.0f + __expf(-xv)));
}

__global__ __launch_bounds__(256) void combine4_kernel(
    const float4* __restrict__ p, float4* __restrict__ out) {
  const int idx = blockIdx.x * 256 + (int)threadIdx.x;
  const float4 a = p[idx];
  const float4 b = p[idx + 524288];
  const float4 c = p[idx + 1048576];
  const float4 d = p[idx + 1572864];
  out[idx] =
      make_float4(a.x + b.x + c.x + d.x, a.y + b.y + c.y + d.y,
                  a.z + b.z + c.z + d.z, a.w + b.w + c.w + d.w);
}

// ---------------------------------------------------------------------------
extern "C" void kernel_launch(void* const* d_in, const int* in_sizes, int n_in,
                              void* d_out, int out_size, void* d_ws,
                              size_t ws_size, hipStream_t stream) {
  const float* tok[3] = {(const float*)d_in[0], (const float*)d_in[1],
                         (const float*)d_in[2]};
  const float* wq = (const float*)d_in[3];
  const float* bq = (const float*)d_in[4];
  const float* wk = (const float*)d_in[5];
  const float* bk = (const float*)d_in[6];
  const float* wv = (const float*)d_in[7];
  const float* bv = (const float*)d_in[8];
  // d_in[9] view_emb unused (softmax-invariant)
  const float* lng[3] = {(const float*)d_in[10], (const float*)d_in[12],
                         (const float*)d_in[14]};
  const float* lnb[3] = {(const float*)d_in[11], (const float*)d_in[13],
                         (const float*)d_in[15]};
  const float* bw = (const float*)d_in[16];
  const float* sw = (const float*)d_in[17];
  const float* scaler = (const float*)d_in[18];

  // fused layout (R13, total 169,085,952 B <= known-safe 194,776,064):
  //   basis @0 (113,246,208) -- written by resid_ln AFTER attention; until
  //     then sub-aliased: tokb @0 (12.58M) | qkv @12,582,912 (37.75M) |
  //     vT @50,331,648 (12.58M, ends 62,914,560)
  //   attb (bf16 partials, 24 x 2,097,152 B) @113,246,208 -> 163,577,856
  //   lpart_f @163,577,856 (1.57M) -> 165,150,720
  //   Wmat @165,150,720 (3.54M) | wqkvb @168,689,664 | bqkv @169,082,880
  //   KAN split-K accumulates via atomicAdd into d_out (zero_out first).
  // fallback (unchanged): Pb @62,914,560 | lpart @130,023,424 |
  //   attp @132,120,576 | x @165,675,008 | basis aliases [0,..) |
  //   Wmat @190,840,832 | pout aliases attp.
  const bool fused = ws_size >= 169085952ull;
  char* w8 = (char*)d_ws;
  bf16* tokb = (bf16*)(w8 + 0);
  bf16* qkv = (bf16*)(w8 + 12582912);
  bf16* vT = (bf16*)(w8 + 50331648);
  float* x;
  bf16* basis;
  bf16* Wmat;
  float* pout;
  // fallback pointers
  bf16* Pb = (bf16*)(w8 + 62914560);
  float* lpart = (float*)(w8 + 130023424);
  float* attp = (float*)(w8 + 132120576);
  // fused pointers
  bf16* attb = (bf16*)(w8 + 113246208);
  float* lpart_f = (float*)(w8 + 163577856);
  if (fused) {
    x = nullptr;
    basis = (bf16*)(w8 + 0);
    Wmat = (bf16*)(w8 + 165150720);
    pout = nullptr;  // split-K goes straight to d_out via atomics
  } else {
    x = (float*)(w8 + 165675008);
    basis = (bf16*)(w8 + 0);
    Wmat = (bf16*)(w8 + 190840832);
    pout = attp;  // 4 x 8.39 MB, attp dead
  }
  bf16* wqkvb = (bf16*)((char*)Wmat + 3538944);
  float* bqkv = (float*)((char*)wqkvb + 393216);

  prep_all<<<7168, 256, 0, stream>>>(bw, sw, scaler, Wmat, wq, wk, wv, bq, bk,
                                     bv, wqkvb, bqkv, (const float4*)tok[0],
                                     (const float4*)tok[1],
                                     (const float4*)tok[2], tokb);

  // QKV all views: [24576,256] @ [768,256]^T + bias -> qkv bf16
  mfma_gemm_bt<bf16, false><<<dim3(6, 192, 1), 256, 0, stream>>>(
      tokb, wqkvb, bqkv, qkv, nullptr, 256, 256, 256, 768, 1, 0, 0, 0, 0, 0,
      0, 1.0f);
  transpose_v<<<dim3(64, 4, 6), 256, 0, stream>>>(qkv, vT);

  if (fused) {
    // fused flash attention: all views/batches/splits in one dispatch
    fused_attn<<<dim3(32, 24), 512, 0, stream>>>(qkv, vT, attb, lpart_f);
    for (int v = 0; v < 3; ++v)
      resid_ln_kernel<true, bf16><<<8192, 256, 0, stream>>>(
          attb + (size_t)v * 8388608, lpart_f + (size_t)v * 131072, tok[v],
          lng[v], lnb[v], nullptr, basis, 16, v);
    // KAN split-K=6 (z=6, 768 blocks = 3/CU), atomicAdd into zeroed d_out
    zero_out<<<2048, 256, 0, stream>>>((float4*)d_out);
    mfma_gemm_bt<float, false, true><<<dim3(2, 64, 6), 256, 0, stream>>>(
        basis, Wmat, nullptr, (float*)d_out, nullptr, 1152, 6912, 6912, 256,
        3, 0, 1152, 0, 1152, 0, 0, 1.0f);
  } else {
    for (int v = 0; v < 3; ++v) {
      const bf16* qb = qkv + (size_t)(2 * v) * 4096 * 768;
      // scores both batches (z=2): P = exp(q@k^T/16) bf16 + lpart partials
      mfma_gemm_bt<bf16, true><<<dim3(32, 32, 2), 256, 0, stream>>>(
          qb, qb + 256, nullptr, Pb, lpart, 256, 768, 768, 4096, 1, 0,
          3145728, 0, 3145728, 16777216, 262144, 0.0625f);
      // PV split-K=4 x batch (z=8): attp[z] = P-slice @ vT-slice^T
      mfma_gemm_bt<float, false><<<dim3(2, 32, 8), 256, 0, stream>>>(
          Pb, vT + (size_t)(2 * v) * 1048576, nullptr, attp, nullptr, 1024,
          4096, 4096, 256, 2, 16777216, 1024, 1048576, 1024, 1048576, 0, 1.0f);
      resid_ln_kernel<false, float><<<8192, 256, 0, stream>>>(
          attp, lpart, tok[v], lng[v], lnb[v], x, nullptr, 64, v);
    }
    basis_kernel<<<dim3(3, 8192), 256, 0, stream>>>(x, basis);
    mfma_gemm_bt<float, false><<<dim3(2, 64, 4), 256, 0, stream>>>(
        basis, Wmat, nullptr, pout, nullptr, 1728, 6912, 6912, 256, 2, 0,
        1728, 0, 1728, 2097152, 0, 1.0f);
    combine4_kernel<<<2048, 256, 0, stream>>>((const float4*)pout,
                                              (float4*)d_out);
  }
}

// Round 13
// 392.696 us; speedup vs baseline: 1.1360x; 1.0569x over previous
//
#include <hip/hip_runtime.h>
#include <hip/hip_bf16.h>
#include <math.h>

// ---------------------------------------------------------------------------
// B=2, S=4096, D=256, IN=768, N_BASIS=8, spline grid h=0.4
// view_emb adds a row-constant to pre-softmax scores -> cancelled -> unused.
// Softmax without max-subtraction: |q.k|/16 <= ~1.7 -> exp in [0.2,5.5] ->
// online softmax is LINEAR: O = sum exp(s)v, l = sum exp(s).
// R23: R22 measured the atomic-KAN structure at 415us — a 16us REGRESSION
// vs R17 (398.9). fused_attn itself improved (166.5 vs 174.6) but the KAN
// split-K=6 atomicAdd epilogue (12.6M fp32 atomics, 6-way contention on
// 2M words) cost ~35-40us vs the ~22us pout+combine6 round-trip it
// replaced. Revert: KAN -> non-atomic split-K into pout (aliases dead attb)
// + combine6. Keep prep_all merge and the R17 fused_attn verbatim.
// R13: fused layout 169.1MB; attp partials bf16. R11: sched_barrier pins.
// ---------------------------------------------------------------------------

typedef __hip_bfloat16 bf16;
using bf16x8 = __attribute__((ext_vector_type(8))) __bf16;
using f32x4  = __attribute__((ext_vector_type(4))) float;

__device__ __forceinline__ void load_lds16(const void* g, void* l) {
  __builtin_amdgcn_global_load_lds((__attribute__((address_space(1))) void*)g,
                                   (__attribute__((address_space(3))) void*)l,
                                   16, 0, 0);
}

__device__ __forceinline__ float wave_sum(float v) {
#pragma unroll
  for (int o = 32; o > 0; o >>= 1) v += __shfl_down(v, o, 64);
  return v;
}

__device__ __forceinline__ float to_f32(float v) { return v; }
__device__ __forceinline__ float to_f32(bf16 v) { return __bfloat162float(v); }

// closed-form cardinal cubic B-spline segment (validated R7)
__device__ __forceinline__ float b3_cardinal(float x, float tofs) {
  const float t = fmaf(x, 2.5f, tofs);
  const float tc = fminf(fmaxf(t, 0.0f), 4.0f);
  const float p2 = fmaxf(tc - 1.0f, 0.0f);
  const float p3 = fmaxf(tc - 2.0f, 0.0f);
  const float p4 = fmaxf(tc - 3.0f, 0.0f);
  return (tc * tc * tc - 4.0f * p2 * p2 * p2 + 6.0f * p3 * p3 * p3 -
          4.0f * p4 * p4 * p4) * (1.0f / 6.0f);
}

// ---------------------------------------------------------------------------
// bf16 MFMA GEMM, BT form, BK=64 (proven): used by QKV + KAN (+ fallback).
// ---------------------------------------------------------------------------
template <typename OutT, bool EXP>
__global__ __launch_bounds__(256) void mfma_gemm_bt(
    const bf16* __restrict__ A, const bf16* __restrict__ B,
    const float* __restrict__ bias, OutT* __restrict__ C,
    float* __restrict__ lpart, int K, int lda, int ldb, int ldc, int zshift,
    size_t zAh, size_t zAl, size_t zBh, size_t zBl, size_t zC, size_t zL,
    float scale) {
  __shared__ __align__(16) bf16 As[8192];  // 128 x 64
  __shared__ __align__(16) bf16 Bs[8192];
  const int tid = (int)threadIdx.x;
  const int lane = tid & 63;
  const int w = tid >> 6;
  const int m0 = (int)blockIdx.y << 7;
  const int n0 = (int)blockIdx.x << 7;
  const size_t z = blockIdx.z;
  const size_t zlo = z & (((size_t)1 << zshift) - 1);
  A += (z >> zshift) * zAh + zlo * zAl;
  B += (z >> zshift) * zBh + zlo * zBl;
  C += z * zC;
  if (EXP) lpart += z * zL;

  // staging geometry
  const int srow8 = lane >> 3;  // row within 8-row chunk
  const int g8 = (lane & 4) | ((lane & 3) ^ ((lane >> 4) & 3));
  const bf16* gA[4];
  const bf16* gB[4];
  bf16* lA[4];
  bf16* lB[4];
#pragma unroll
  for (int j = 0; j < 4; ++j) {
    const int c = w + 4 * j;
    gA[j] = A + (size_t)(m0 + c * 8 + srow8) * lda + g8 * 8;
    gB[j] = B + (size_t)(n0 + c * 8 + srow8) * ldb + g8 * 8;
    lA[j] = As + c * 512;
    lB[j] = Bs + c * 512;
  }

  // fragment geometry
  const int m15 = lane & 15, quad = lane >> 4;
  const int fq = quad ^ ((m15 >> 1) & 3);
  const bf16* pA = As + (size_t)(((w >> 1) << 6) + m15) * 64 + fq * 8;
  const bf16* pB = Bs + (size_t)(((w & 1) << 6) + m15) * 64 + fq * 8;

  f32x4 acc[4][4];
#pragma unroll
  for (int mi = 0; mi < 4; ++mi)
#pragma unroll
    for (int ni = 0; ni < 4; ++ni) acc[mi][ni] = (f32x4)(0.0f);

  for (int k0 = 0; k0 < K; k0 += 64) {
#pragma unroll
    for (int j = 0; j < 4; ++j) {
      load_lds16(gA[j], lA[j]);
      load_lds16(gB[j], lB[j]);
      gA[j] += 64;
      gB[j] += 64;
    }
    __syncthreads();
    __builtin_amdgcn_sched_barrier(0);  // ds_reads must not hoist above barrier
    bf16x8 av[4][2], bv[4][2];
#pragma unroll
    for (int mi = 0; mi < 4; ++mi)
#pragma unroll
      for (int sub = 0; sub < 2; ++sub) {
        av[mi][sub] = *(const bf16x8*)(pA + mi * 1024 + sub * 32);
        bv[mi][sub] = *(const bf16x8*)(pB + mi * 1024 + sub * 32);
      }
#pragma unroll
    for (int sub = 0; sub < 2; ++sub)
#pragma unroll
      for (int mi = 0; mi < 4; ++mi)
#pragma unroll
        for (int ni = 0; ni < 4; ++ni)
          acc[mi][ni] = __builtin_amdgcn_mfma_f32_16x16x32_bf16(
              av[mi][sub], bv[ni][sub], acc[mi][ni], 0, 0, 0);
    __builtin_amdgcn_sched_barrier(0);  // reads/MFMAs must not sink below
    __syncthreads();
    __builtin_amdgcn_sched_barrier(0);  // next-iter LDS-DMA must not hoist
  }

  const int crow = m0 + ((w >> 1) << 6) + quad * 4;
  const int ccol = n0 + ((w & 1) << 6) + m15;
  float rs[4][4] = {};
#pragma unroll
  for (int ni = 0; ni < 4; ++ni) {
    const int col = ccol + ni * 16;
    const float bb = bias ? bias[col] : 0.0f;
#pragma unroll
    for (int mi = 0; mi < 4; ++mi) {
#pragma unroll
      for (int i = 0; i < 4; ++i) {
        const int row = crow + mi * 16 + i;
        float v = acc[mi][ni][i] * scale + bb;
        if constexpr (EXP) {
          v = __expf(v);
          rs[mi][i] += v;
        }
        if constexpr (sizeof(OutT) == 2)
          C[(size_t)row * ldc + col] = __float2bfloat16(v);
        else
          C[(size_t)row * ldc + col] = v;
      }
    }
  }
  if constexpr (EXP) {
    const int ch = ((int)blockIdx.x << 1) | (w & 1);
#pragma unroll
    for (int mi = 0; mi < 4; ++mi)
#pragma unroll
      for (int i = 0; i < 4; ++i) {
        float sv = rs[mi][i];
        sv += __shfl_xor(sv, 1);
        sv += __shfl_xor(sv, 2);
        sv += __shfl_xor(sv, 4);
        sv += __shfl_xor(sv, 8);
        if (m15 == 0)
          lpart[(size_t)ch * 4096 + crow + mi * 16 + i] = sv;
      }
  }
}

// ---------------------------------------------------------------------------
// fused flash attention — EXACT R17 configuration (measured 166.5-174.6us):
// Block: 512 thr = 8 waves (2 wm x 4 wn). Q-tile 128 rows, split of 1024
// keys = 16 tiles x 64 keys. grid = (32 Qtiles, 24 = v*8 + b*4 + sp).
// LDS 80KB (Ks 32K + Vs 32K + Ps 16K), launch_bounds(512,2) -> VGPR 128.
// Single K/V buffers; K(t+1) staged after mid barrier (drain hidden under
// PV), V(t+1) staged after end barrier (drain hidden under next S). Ps
// [128][64] granule swizzle p=(k>>3)^(2*((r>>2)&3)): conflict-free r/w.
// Outputs: attp bf16 partials + lpart 16 ch/(batch,view).
// ---------------------------------------------------------------------------
__global__ __launch_bounds__(512, 2) void fused_attn(
    const bf16* __restrict__ qkv, const bf16* __restrict__ vT,
    bf16* __restrict__ attp, float* __restrict__ lpart) {
  __shared__ __align__(16) bf16 Ks[16384];  // 4 subtiles 64(keys)x64(k)
  __shared__ __align__(16) bf16 Vs[16384];  // 4 rowgroups 64(d)x64(key)
  __shared__ __align__(16) bf16 Ps[8192];   // 128 x 64, granule-swizzled
  const int tid = (int)threadIdx.x;
  const int lane = tid & 63;
  const int w = tid >> 6;   // 0..7
  const int wm = w >> 2;    // 0..1 : Q-row half
  const int wn = w & 3;     // 0..3 : S key-16-col / O d-64-col
  const int bx = (int)blockIdx.x;           // Q-tile
  const int by = (int)blockIdx.y;           // v*8 + b*4 + sp
  const int v = by >> 3, b = (by >> 2) & 1, sp = by & 3;
  const bf16* qb = qkv + (size_t)((v * 2 + b) * 4096) * 768;
  const bf16* vb = vT + (size_t)(v * 2 + b) * 1048576;
  attp += (size_t)by * 1048576;

  const int srow8 = lane >> 3;
  const int g8 = (lane & 4) | ((lane & 3) ^ ((lane >> 4) & 3));
  const int m15 = lane & 15, quad = lane >> 4;
  const int fq = quad ^ ((m15 >> 1) & 3);
  const int key0 = sp * 1024;

  // staging bases (chunk c = w of each 64x64 subtile)
  const bf16* gKb = qb + (size_t)(key0 + w * 8 + srow8) * 768 + 256 + g8 * 8;
  const bf16* gVb = vb + (size_t)(w * 8 + srow8) * 4096 + key0 + g8 * 8;

#define STAGE_K(T)                                               \
  do {                                                           \
    const bf16* gk_ = gKb + (size_t)(T) * 49152;                 \
    bf16* lk_ = Ks + w * 512;                                    \
    _Pragma("unroll") for (int j_ = 0; j_ < 4; ++j_)             \
        load_lds16(gk_ + j_ * 64, lk_ + j_ * 4096);              \
  } while (0)
#define STAGE_V(T)                                               \
  do {                                                           \
    const bf16* gv_ = gVb + (T) * 64;                            \
    bf16* lv_ = Vs + w * 512;                                    \
    _Pragma("unroll") for (int j_ = 0; j_ < 4; ++j_)             \
        load_lds16(gv_ + (size_t)j_ * 262144, lv_ + j_ * 4096);  \
  } while (0)

  STAGE_K(0);
  STAGE_V(0);

  // full Q fragments (compiler keeps/remats under the 128-VGPR cap;
  // re-loads are L1/L2 hits)
  bf16x8 qreg[4][8];
  const int qrow = bx * 128 + wm * 64 + m15;
#pragma unroll
  for (int mf = 0; mf < 4; ++mf)
#pragma unroll
    for (int ks = 0; ks < 8; ++ks)
      qreg[mf][ks] = *(const bf16x8*)(qb + (size_t)(qrow + mf * 16) * 768 +
                                      ks * 32 + quad * 8);

  f32x4 oacc[4][4];
#pragma unroll
  for (int mi = 0; mi < 4; ++mi)
#pragma unroll
    for (int ni = 0; ni < 4; ++ni) oacc[mi][ni] = (f32x4)(0.0f);
  float rs[4][4] = {};

  __syncthreads();  // drain tile-0 K/V DMAs + qreg loads
  __builtin_amdgcn_sched_barrier(0);

  const bf16* pKr = Ks + (wn * 16 + m15) * 64 + fq * 8;
  const bf16* pVr = Vs + wn * 4096 + m15 * 64 + fq * 8;
  // P write: row r = wm*64 + mf*16 + quad*4 + i, col k = wn*16 + m15;
  // granule p = (k>>3) ^ (2*((r>>2)&3)) = gP ^ (quad<<1)  (mf,i drop out)
  const int gP = wn * 2 + (m15 >> 3);
  bf16* pPw = Ps + (wm * 64 + quad * 4) * 64 + ((gP ^ (quad << 1)) << 3) +
              (m15 & 7);
  // P read: row r = wm*64 + m15 + mi*16 -> (r>>2)&3 = (m15>>2)&3
  const int xr = ((m15 >> 2) & 3) << 1;
  const bf16* pPr = Ps + (wm * 64 + m15) * 64;

  for (int t = 0; t < 16; ++t) {
    // ---- S phase: sacc[mf] = Q @ K^T, wave tile 64 rows x 16 keys
    f32x4 sacc[4];
#pragma unroll
    for (int mf = 0; mf < 4; ++mf) sacc[mf] = (f32x4)(0.0f);
#pragma unroll
    for (int ks = 0; ks < 8; ++ks) {
      const bf16x8 bvk =
          *(const bf16x8*)(pKr + (ks >> 1) * 4096 + (ks & 1) * 32);
#pragma unroll
      for (int mf = 0; mf < 4; ++mf)
        sacc[mf] = __builtin_amdgcn_mfma_f32_16x16x32_bf16(qreg[mf][ks], bvk,
                                                           sacc[mf], 0, 0, 0);
    }
    // ---- exp + P write (swizzled, conflict-free) + row-sum accumulate
#pragma unroll
    for (int mf = 0; mf < 4; ++mf)
#pragma unroll
      for (int i = 0; i < 4; ++i) {
        const float pe = exp2f(sacc[mf][i] * 0.09016844136f);  // /16 * log2 e
        rs[mf][i] += pe;
        pPw[mf * 1024 + i * 64] = __float2bfloat16(pe);
      }
    __builtin_amdgcn_sched_barrier(0);
    __syncthreads();  // mid: Ps visible; Ks(t) dead; V(t) DMA long drained
    __builtin_amdgcn_sched_barrier(0);
    if (t < 15) STAGE_K(t + 1);  // drains at end barrier, hidden under PV
    // ---- PV: oacc += P @ V ; wave tile 64 rows x 64 d
#pragma unroll
    for (int sub = 0; sub < 2; ++sub) {
      bf16x8 pa[4], bvv[4];
#pragma unroll
      for (int mi = 0; mi < 4; ++mi)
        pa[mi] = *(const bf16x8*)(pPr + mi * 1024 +
                                  ((((sub << 2) | quad) ^ xr) << 3));
#pragma unroll
      for (int ni = 0; ni < 4; ++ni)
        bvv[ni] = *(const bf16x8*)(pVr + ni * 1024 + sub * 32);
#pragma unroll
      for (int mi = 0; mi < 4; ++mi)
#pragma unroll
        for (int ni = 0; ni < 4; ++ni)
          oacc[mi][ni] = __builtin_amdgcn_mfma_f32_16x16x32_bf16(
              pa[mi], bvv[ni], oacc[mi][ni], 0, 0, 0);
    }
    __builtin_amdgcn_sched_barrier(0);
    __syncthreads();  // end: Vs(t)+Ps dead; K(t+1) DMA drained here
    __builtin_amdgcn_sched_barrier(0);
    if (t < 15) STAGE_V(t + 1);  // drains at next mid barrier, hidden under S
  }
#undef STAGE_K
#undef STAGE_V

  // ---- epilogue: O partials (bf16) + lpart channel (b*16 + sp*4 + wn)
  const int crow0 = bx * 128 + wm * 64 + quad * 4;
  const int ccol0 = wn * 64 + m15;
#pragma unroll
  for (int mi = 0; mi < 4; ++mi)
#pragma unroll
    for (int ni = 0; ni < 4; ++ni)
#pragma unroll
      for (int i = 0; i < 4; ++i)
        attp[(size_t)(crow0 + mi * 16 + i) * 256 + ccol0 + ni * 16] =
            __float2bfloat16(oacc[mi][ni][i]);
  float* lp = lpart + (size_t)v * 131072 +
              (size_t)(b * 16 + sp * 4 + wn) * 4096 + bx * 128 + wm * 64;
#pragma unroll
  for (int mf = 0; mf < 4; ++mf)
#pragma unroll
    for (int i = 0; i < 4; ++i) {
      float sv = rs[mf][i];
      sv += __shfl_xor(sv, 1);
      sv += __shfl_xor(sv, 2);
      sv += __shfl_xor(sv, 4);
      sv += __shfl_xor(sv, 8);
      if (m15 == 0) lp[mf * 16 + quad * 4 + i] = sv;
    }
}

// ---------------------------------------------------------------------------
// residual + LayerNorm from split-K PV partials and lpart row sums.
// PT = partial dtype: bf16 (fused) / float (fallback). nch lpart channels.
// FUSE=true : emit 9 bf16 KAN basis channels directly (no x buffer).
// ---------------------------------------------------------------------------
template <bool FUSE, typename PT>
__global__ __launch_bounds__(256) void resid_ln_kernel(
    const PT* __restrict__ attp, const float* __restrict__ lpart,
    const float* __restrict__ tok, const float* __restrict__ gamma,
    const float* __restrict__ beta, float* __restrict__ xout,
    bf16* __restrict__ basis, int nch, int vIdx) {
  __shared__ float red[4];
  __shared__ float sinvl;
  __shared__ __align__(16) bf16 st[2304];  // 256 elems x 9 channels
  const int n = (int)blockIdx.x;  // 0..8191 ; b = n>>12
  const int d = (int)threadIdx.x;
  const int b = n >> 12, r = n & 4095;
  float ls = 0.f;
  if (d < nch) ls = lpart[((size_t)(b * nch + d)) * 4096 + r];
  ls = wave_sum(ls);
  if (d == 0) sinvl = 1.0f / ls;
  const size_t abase = (size_t)(b * 4) * 1048576 + (size_t)r * 256 + d;
  const float asum = to_f32(attp[abase]) + to_f32(attp[abase + 1048576]) +
                     to_f32(attp[abase + 2097152]) +
                     to_f32(attp[abase + 3145728]);
  __syncthreads();
  const float y = asum * sinvl + tok[(size_t)n * 256 + d];
  float s = wave_sum(y);
  if ((d & 63) == 0) red[d >> 6] = s;
  __syncthreads();
  const float mu = (red[0] + red[1] + red[2] + red[3]) * (1.0f / 256.0f);
  __syncthreads();
  const float c = y - mu;
  float s2 = wave_sum(c * c);
  if ((d & 63) == 0) red[d >> 6] = s2;
  __syncthreads();
  const float var = (red[0] + red[1] + red[2] + red[3]) * (1.0f / 256.0f);
  const float rstd = rsqrtf(var + 1e-5f);
  const float val = c * rstd * gamma[d] + beta[d];
  if constexpr (!FUSE) {
    xout[(size_t)n * 768 + vIdx * 256 + d] = val;
  } else {
#pragma unroll
    for (int f = 0; f < 8; ++f)
      st[d * 9 + f] = __float2bfloat16(b3_cardinal(val, 5.5f - (float)f));
    st[d * 9 + 8] = __float2bfloat16(val / (1.0f + __expf(-val)));
    __syncthreads();
    float4* gb = (float4*)((char*)basis + (size_t)n * 13824 + vIdx * 4608);
    const float4* sb = (const float4*)st;
    gb[d] = sb[d];
    if (d < 32) gb[256 + d] = sb[256 + d];
  }
}

// ---------------------------------------------------------------------------
// merged prep: blocks 0..255 = prep_w ; 256..1023 = prep_qkvw ;
// 1024..7167 = cast_tok3 (2048 blocks per view).
// ---------------------------------------------------------------------------
__global__ __launch_bounds__(256) void prep_all(
    const float* __restrict__ bw, const float* __restrict__ sw,
    const float* __restrict__ scaler, bf16* __restrict__ Wmat,
    const float* __restrict__ wq, const float* __restrict__ wk,
    const float* __restrict__ wv, const float* __restrict__ bq,
    const float* __restrict__ bk, const float* __restrict__ bv,
    bf16* __restrict__ wqkvb, float* __restrict__ bqkv,
    const float4* __restrict__ t0, const float4* __restrict__ t1,
    const float4* __restrict__ t2, bf16* __restrict__ tokb) {
  const int bid = (int)blockIdx.x;
  const int tid = (int)threadIdx.x;
  if (bid < 256) {
    const int o = bid;
    for (int ii = 0; ii < 3; ++ii) {
      const int i = ii * 256 + tid;
      const float s = scaler[(size_t)o * 768 + i];
      bf16* p = Wmat + (size_t)o * 6912 + i * 9;
      const float* swp = sw + ((size_t)o * 768 + i) * 8;
#pragma unroll
      for (int f = 0; f < 8; ++f) p[f] = __float2bfloat16(swp[f] * s);
      p[8] = __float2bfloat16(bw[(size_t)o * 768 + i]);
    }
  } else if (bid < 1024) {
    const int idx = (bid - 256) * 256 + tid;
    const int row = idx >> 8, col = idx & 255;
    const float* src = row < 256 ? wq : (row < 512 ? wk : wv);
    wqkvb[idx] = __float2bfloat16(src[((row & 255) << 8) + col]);
    if (idx < 768)
      bqkv[idx] =
          idx < 256 ? bq[idx] : (idx < 512 ? bk[idx - 256] : bv[idx - 512]);
  } else {
    const int f = bid - 1024;
    const int vv = f >> 11;
    const int idx = (f & 2047) * 256 + tid;
    const float4* src = vv == 0 ? t0 : (vv == 1 ? t1 : t2);
    const float4 val = src[idx];
    bf16* p = tokb + (size_t)vv * 2097152 + (size_t)idx * 4;
    p[0] = __float2bfloat16(val.x);
    p[1] = __float2bfloat16(val.y);
    p[2] = __float2bfloat16(val.z);
    p[3] = __float2bfloat16(val.w);
  }
}

// vT[z][d][s] = qkv[z*4096+s][512+d]
__global__ __launch_bounds__(256) void transpose_v(
    const bf16* __restrict__ qkv, bf16* __restrict__ vT) {
  __shared__ bf16 tle[64][65];
  const int s0 = blockIdx.x << 6, d0 = blockIdx.y << 6, z = blockIdx.z;
  const int tid = (int)threadIdx.x;
  const int c = tid & 63, rr = tid >> 6;
  for (int r = 0; r < 64; r += 4)
    tle[r + rr][c] = qkv[(size_t)(z * 4096 + s0 + r + rr) * 768 + 512 + d0 + c];
  __syncthreads();
  for (int r = 0; r < 64; r += 4)
    vT[(size_t)z * 1048576 + (size_t)(d0 + r + rr) * 4096 + s0 + c] =
        tle[c][r + rr];
}

// ---------------------------------------------------------------------------
// fallback basis: basis[n][i*9+f] from x (Cox-de-Boor, proven R6)
// ---------------------------------------------------------------------------
__global__ __launch_bounds__(256) void basis_kernel(
    const float* __restrict__ x, bf16* __restrict__ basis) {
  const int i = blockIdx.x * 256 + (int)threadIdx.x;  // 0..767
  const int n = blockIdx.y;
  const float xv = x[(size_t)n * 768 + i];
  float b[11];
#pragma unroll
  for (int m = 0; m < 11; ++m) {
    const float g0 = 0.4f * (float)(m - 3) - 1.0f;
    const float g1 = 0.4f * (float)(m - 2) - 1.0f;
    b[m] = (xv >= g0 && xv < g1) ? 1.0f : 0.0f;
  }
#pragma unroll
  for (int k = 1; k <= 3; ++k) {
    const float inv = 1.0f / (0.4f * (float)k);
#pragma unroll
    for (int m = 0; m + k < 11; ++m) {
      const float gm = 0.4f * (float)(m - 3) - 1.0f;
      const float gmk1 = 0.4f * (float)(m + k - 2) - 1.0f;
      b[m] = (xv - gm) * inv * b[m] + (gmk1 - xv) * inv * b[m + 1];
    }
  }
  bf16* p = basis + (size_t)n * 6912 + i * 9;
#pragma unroll
  for (int f = 0; f < 8; ++f) p[f] = __float2bfloat16(b[f]);
  p[8] = __float2bfloat16(xv / (1.0f + __expf(-xv)));
}

__global__ __launch_bounds__(256) void combine4_kernel(
    const float4* __restrict__ p, float4* __restrict__ out) {
  const int idx = blockIdx.x * 256 + (int)threadIdx.x;
  const float4 a = p[idx];
  const float4 b = p[idx + 524288];
  const float4 c = p[idx + 1048576];
  const float4 d = p[idx + 1572864];
  out[idx] =
      make_float4(a.x + b.x + c.x + d.x, a.y + b.y + c.y + d.y,
                  a.z + b.z + c.z + d.z, a.w + b.w + c.w + d.w);
}

__global__ __launch_bounds__(256) void combine6_kernel(
    const float4* __restrict__ p, float4* __restrict__ out) {
  const int idx = blockIdx.x * 256 + (int)threadIdx.x;
  float4 s = p[idx];
#pragma unroll
  for (int j = 1; j < 6; ++j) {
    const float4 a = p[idx + (size_t)j * 524288];
    s.x += a.x;
    s.y += a.y;
    s.z += a.z;
    s.w += a.w;
  }
  out[idx] = s;
}

// ---------------------------------------------------------------------------
extern "C" void kernel_launch(void* const* d_in, const int* in_sizes, int n_in,
                              void* d_out, int out_size, void* d_ws,
                              size_t ws_size, hipStream_t stream) {
  const float* tok[3] = {(const float*)d_in[0], (const float*)d_in[1],
                         (const float*)d_in[2]};
  const float* wq = (const float*)d_in[3];
  const float* bq = (const float*)d_in[4];
  const float* wk = (const float*)d_in[5];
  const float* bk = (const float*)d_in[6];
  const float* wv = (const float*)d_in[7];
  const float* bv = (const float*)d_in[8];
  // d_in[9] view_emb unused (softmax-invariant)
  const float* lng[3] = {(const float*)d_in[10], (const float*)d_in[12],
                         (const float*)d_in[14]};
  const float* lnb[3] = {(const float*)d_in[11], (const float*)d_in[13],
                         (const float*)d_in[15]};
  const float* bw = (const float*)d_in[16];
  const float* sw = (const float*)d_in[17];
  const float* scaler = (const float*)d_in[18];

  // fused layout (R13, total 169,085,952 B <= known-safe 194,776,064):
  //   basis @0 (113,246,208) -- written by resid_ln AFTER attention; until
  //     then sub-aliased: tokb @0 (12.58M) | qkv @12,582,912 (37.75M) |
  //     vT @50,331,648 (12.58M, ends 62,914,560)
  //   attb (bf16 partials, 24 x 2,097,152 B) @113,246,208 -> 163,577,856
  //   lpart_f @163,577,856 (1.57M) -> 165,150,720
  //   Wmat @165,150,720 (3.54M) | wqkvb @168,689,664 | bqkv @169,082,880
  //   pout (KAN z=6, 50,331,648 B fp32) aliases attb (dead after resid_ln)
  // fallback (unchanged): Pb @62,914,560 | lpart @130,023,424 |
  //   attp @132,120,576 | x @165,675,008 | basis aliases [0,..) |
  //   Wmat @190,840,832 | pout aliases attp.
  const bool fused = ws_size >= 169085952ull;
  char* w8 = (char*)d_ws;
  bf16* tokb = (bf16*)(w8 + 0);
  bf16* qkv = (bf16*)(w8 + 12582912);
  bf16* vT = (bf16*)(w8 + 50331648);
  float* x;
  bf16* basis;
  bf16* Wmat;
  float* pout;
  // fallback pointers
  bf16* Pb = (bf16*)(w8 + 62914560);
  float* lpart = (float*)(w8 + 130023424);
  float* attp = (float*)(w8 + 132120576);
  // fused pointers
  bf16* attb = (bf16*)(w8 + 113246208);
  float* lpart_f = (float*)(w8 + 163577856);
  if (fused) {
    x = nullptr;
    basis = (bf16*)(w8 + 0);
    Wmat = (bf16*)(w8 + 165150720);
    pout = (float*)(w8 + 113246208);  // attb dead after resid_ln
  } else {
    x = (float*)(w8 + 165675008);
    basis = (bf16*)(w8 + 0);
    Wmat = (bf16*)(w8 + 190840832);
    pout = attp;  // 4 x 8.39 MB, attp dead
  }
  bf16* wqkvb = (bf16*)((char*)Wmat + 3538944);
  float* bqkv = (float*)((char*)wqkvb + 393216);

  prep_all<<<7168, 256, 0, stream>>>(bw, sw, scaler, Wmat, wq, wk, wv, bq, bk,
                                     bv, wqkvb, bqkv, (const float4*)tok[0],
                                     (const float4*)tok[1],
                                     (const float4*)tok[2], tokb);

  // QKV all views: [24576,256] @ [768,256]^T + bias -> qkv bf16
  mfma_gemm_bt<bf16, false><<<dim3(6, 192, 1), 256, 0, stream>>>(
      tokb, wqkvb, bqkv, qkv, nullptr, 256, 256, 256, 768, 1, 0, 0, 0, 0, 0,
      0, 1.0f);
  transpose_v<<<dim3(64, 4, 6), 256, 0, stream>>>(qkv, vT);

  if (fused) {
    // fused flash attention: all views/batches/splits in one dispatch
    fused_attn<<<dim3(32, 24), 512, 0, stream>>>(qkv, vT, attb, lpart_f);
    for (int v = 0; v < 3; ++v)
      resid_ln_kernel<true, bf16><<<8192, 256, 0, stream>>>(
          attb + (size_t)v * 8388608, lpart_f + (size_t)v * 131072, tok[v],
          lng[v], lnb[v], nullptr, basis, 16, v);
    // KAN split-K=6 (z=6, 768 blocks = 3/CU): slice K=1152
    mfma_gemm_bt<float, false><<<dim3(2, 64, 6), 256, 0, stream>>>(
        basis, Wmat, nullptr, pout, nullptr, 1152, 6912, 6912, 256, 3, 0,
        1152, 0, 1152, 2097152, 0, 1.0f);
    combine6_kernel<<<2048, 256, 0, stream>>>((const float4*)pout,
                                              (float4*)d_out);
  } else {
    for (int v = 0; v < 3; ++v) {
      const bf16* qb = qkv + (size_t)(2 * v) * 4096 * 768;
      // scores both batches (z=2): P = exp(q@k^T/16) bf16 + lpart partials
      mfma_gemm_bt<bf16, true><<<dim3(32, 32, 2), 256, 0, stream>>>(
          qb, qb + 256, nullptr, Pb, lpart, 256, 768, 768, 4096, 1, 0,
          3145728, 0, 3145728, 16777216, 262144, 0.0625f);
      // PV split-K=4 x batch (z=8): attp[z] = P-slice @ vT-slice^T
      mfma_gemm_bt<float, false><<<dim3(2, 32, 8), 256, 0, stream>>>(
          Pb, vT + (size_t)(2 * v) * 1048576, nullptr, attp, nullptr, 1024,
          4096, 4096, 256, 2, 16777216, 1024, 1048576, 1024, 1048576, 0, 1.0f);
      resid_ln_kernel<false, float><<<8192, 256, 0, stream>>>(
          attp, lpart, tok[v], lng[v], lnb[v], x, nullptr, 64, v);
    }
    basis_kernel<<<dim3(3, 8192), 256, 0, stream>>>(x, basis);
    mfma_gemm_bt<float, false><<<dim3(2, 64, 4), 256, 0, stream>>>(
        basis, Wmat, nullptr, pout, nullptr, 1728, 6912, 6912, 256, 2, 0,
        1728, 0, 1728, 2097152, 0, 1.0f);
    combine4_kernel<<<2048, 256, 0, stream>>>((const float4*)pout,
                                              (float4*)d_out);
  }
}

// Round 14
// 377.521 us; speedup vs baseline: 1.1817x; 1.0402x over previous
//
#include <hip/hip_runtime.h>
#include <hip/hip_bf16.h>
#include <math.h>

// ---------------------------------------------------------------------------
// B=2, S=4096, D=256, IN=768, N_BASIS=8, spline grid h=0.4
// view_emb adds a row-constant to pre-softmax scores -> cancelled -> unused.
// Softmax without max-subtraction: |q.k|/16 <= ~1.7 -> exp in [0.2,5.5] ->
// online softmax is LINEAR: O = sum exp(s)v, l = sum exp(s).
// R24 (on R23 = 392.7us best: attn 168.8 + rest 223.9):
//  - KAN split-K partials in BF16 (pout 50.3MB fp32 -> 25.2MB bf16; combine6
//    reads bf16): ~-8us. Error +<=5e-3 (absmax 0.0156 -> ~0.02 << 0.0497).
//  - resid_ln merged to ONE dispatch over all 3 views (grid 24576,
//    v = bid>>13, wave-uniform pointer select): -2 launches.
// fused_attn byte-identical to R23/R17 (166-175us measured, occupancy
// immovable at ~22% across 7 variants — accepted). prep_all kept.
// R13: fused layout 169.1MB; attp partials bf16. R11: sched_barrier pins.
// ---------------------------------------------------------------------------

typedef __hip_bfloat16 bf16;
using bf16x8 = __attribute__((ext_vector_type(8))) __bf16;
using f32x4  = __attribute__((ext_vector_type(4))) float;

__device__ __forceinline__ void load_lds16(const void* g, void* l) {
  __builtin_amdgcn_global_load_lds((__attribute__((address_space(1))) void*)g,
                                   (__attribute__((address_space(3))) void*)l,
                                   16, 0, 0);
}

__device__ __forceinline__ float wave_sum(float v) {
#pragma unroll
  for (int o = 32; o > 0; o >>= 1) v += __shfl_down(v, o, 64);
  return v;
}

__device__ __forceinline__ float to_f32(float v) { return v; }
__device__ __forceinline__ float to_f32(bf16 v) { return __bfloat162float(v); }

// closed-form cardinal cubic B-spline segment (validated R7)
__device__ __forceinline__ float b3_cardinal(float x, float tofs) {
  const float t = fmaf(x, 2.5f, tofs);
  const float tc = fminf(fmaxf(t, 0.0f), 4.0f);
  const float p2 = fmaxf(tc - 1.0f, 0.0f);
  const float p3 = fmaxf(tc - 2.0f, 0.0f);
  const float p4 = fmaxf(tc - 3.0f, 0.0f);
  return (tc * tc * tc - 4.0f * p2 * p2 * p2 + 6.0f * p3 * p3 * p3 -
          4.0f * p4 * p4 * p4) * (1.0f / 6.0f);
}

// ---------------------------------------------------------------------------
// bf16 MFMA GEMM, BT form, BK=64 (proven): used by QKV + KAN (+ fallback).
// ---------------------------------------------------------------------------
template <typename OutT, bool EXP>
__global__ __launch_bounds__(256) void mfma_gemm_bt(
    const bf16* __restrict__ A, const bf16* __restrict__ B,
    const float* __restrict__ bias, OutT* __restrict__ C,
    float* __restrict__ lpart, int K, int lda, int ldb, int ldc, int zshift,
    size_t zAh, size_t zAl, size_t zBh, size_t zBl, size_t zC, size_t zL,
    float scale) {
  __shared__ __align__(16) bf16 As[8192];  // 128 x 64
  __shared__ __align__(16) bf16 Bs[8192];
  const int tid = (int)threadIdx.x;
  const int lane = tid & 63;
  const int w = tid >> 6;
  const int m0 = (int)blockIdx.y << 7;
  const int n0 = (int)blockIdx.x << 7;
  const size_t z = blockIdx.z;
  const size_t zlo = z & (((size_t)1 << zshift) - 1);
  A += (z >> zshift) * zAh + zlo * zAl;
  B += (z >> zshift) * zBh + zlo * zBl;
  C += z * zC;
  if (EXP) lpart += z * zL;

  // staging geometry
  const int srow8 = lane >> 3;  // row within 8-row chunk
  const int g8 = (lane & 4) | ((lane & 3) ^ ((lane >> 4) & 3));
  const bf16* gA[4];
  const bf16* gB[4];
  bf16* lA[4];
  bf16* lB[4];
#pragma unroll
  for (int j = 0; j < 4; ++j) {
    const int c = w + 4 * j;
    gA[j] = A + (size_t)(m0 + c * 8 + srow8) * lda + g8 * 8;
    gB[j] = B + (size_t)(n0 + c * 8 + srow8) * ldb + g8 * 8;
    lA[j] = As + c * 512;
    lB[j] = Bs + c * 512;
  }

  // fragment geometry
  const int m15 = lane & 15, quad = lane >> 4;
  const int fq = quad ^ ((m15 >> 1) & 3);
  const bf16* pA = As + (size_t)(((w >> 1) << 6) + m15) * 64 + fq * 8;
  const bf16* pB = Bs + (size_t)(((w & 1) << 6) + m15) * 64 + fq * 8;

  f32x4 acc[4][4];
#pragma unroll
  for (int mi = 0; mi < 4; ++mi)
#pragma unroll
    for (int ni = 0; ni < 4; ++ni) acc[mi][ni] = (f32x4)(0.0f);

  for (int k0 = 0; k0 < K; k0 += 64) {
#pragma unroll
    for (int j = 0; j < 4; ++j) {
      load_lds16(gA[j], lA[j]);
      load_lds16(gB[j], lB[j]);
      gA[j] += 64;
      gB[j] += 64;
    }
    __syncthreads();
    __builtin_amdgcn_sched_barrier(0);  // ds_reads must not hoist above barrier
    bf16x8 av[4][2], bv[4][2];
#pragma unroll
    for (int mi = 0; mi < 4; ++mi)
#pragma unroll
      for (int sub = 0; sub < 2; ++sub) {
        av[mi][sub] = *(const bf16x8*)(pA + mi * 1024 + sub * 32);
        bv[mi][sub] = *(const bf16x8*)(pB + mi * 1024 + sub * 32);
      }
#pragma unroll
    for (int sub = 0; sub < 2; ++sub)
#pragma unroll
      for (int mi = 0; mi < 4; ++mi)
#pragma unroll
        for (int ni = 0; ni < 4; ++ni)
          acc[mi][ni] = __builtin_amdgcn_mfma_f32_16x16x32_bf16(
              av[mi][sub], bv[ni][sub], acc[mi][ni], 0, 0, 0);
    __builtin_amdgcn_sched_barrier(0);  // reads/MFMAs must not sink below
    __syncthreads();
    __builtin_amdgcn_sched_barrier(0);  // next-iter LDS-DMA must not hoist
  }

  const int crow = m0 + ((w >> 1) << 6) + quad * 4;
  const int ccol = n0 + ((w & 1) << 6) + m15;
  float rs[4][4] = {};
#pragma unroll
  for (int ni = 0; ni < 4; ++ni) {
    const int col = ccol + ni * 16;
    const float bb = bias ? bias[col] : 0.0f;
#pragma unroll
    for (int mi = 0; mi < 4; ++mi) {
#pragma unroll
      for (int i = 0; i < 4; ++i) {
        const int row = crow + mi * 16 + i;
        float v = acc[mi][ni][i] * scale + bb;
        if constexpr (EXP) {
          v = __expf(v);
          rs[mi][i] += v;
        }
        if constexpr (sizeof(OutT) == 2)
          C[(size_t)row * ldc + col] = __float2bfloat16(v);
        else
          C[(size_t)row * ldc + col] = v;
      }
    }
  }
  if constexpr (EXP) {
    const int ch = ((int)blockIdx.x << 1) | (w & 1);
#pragma unroll
    for (int mi = 0; mi < 4; ++mi)
#pragma unroll
      for (int i = 0; i < 4; ++i) {
        float sv = rs[mi][i];
        sv += __shfl_xor(sv, 1);
        sv += __shfl_xor(sv, 2);
        sv += __shfl_xor(sv, 4);
        sv += __shfl_xor(sv, 8);
        if (m15 == 0)
          lpart[(size_t)ch * 4096 + crow + mi * 16 + i] = sv;
      }
  }
}

// ---------------------------------------------------------------------------
// fused flash attention — EXACT R17/R23 configuration (166.5-174.6us):
// Block: 512 thr = 8 waves (2 wm x 4 wn). Q-tile 128 rows, split of 1024
// keys = 16 tiles x 64 keys. grid = (32 Qtiles, 24 = v*8 + b*4 + sp).
// LDS 80KB (Ks 32K + Vs 32K + Ps 16K), launch_bounds(512,2) -> VGPR 128.
// Single K/V buffers; K(t+1) staged after mid barrier (drain hidden under
// PV), V(t+1) staged after end barrier (drain hidden under next S). Ps
// [128][64] granule swizzle p=(k>>3)^(2*((r>>2)&3)): conflict-free r/w.
// Outputs: attp bf16 partials + lpart 16 ch/(batch,view).
// ---------------------------------------------------------------------------
__global__ __launch_bounds__(512, 2) void fused_attn(
    const bf16* __restrict__ qkv, const bf16* __restrict__ vT,
    bf16* __restrict__ attp, float* __restrict__ lpart) {
  __shared__ __align__(16) bf16 Ks[16384];  // 4 subtiles 64(keys)x64(k)
  __shared__ __align__(16) bf16 Vs[16384];  // 4 rowgroups 64(d)x64(key)
  __shared__ __align__(16) bf16 Ps[8192];   // 128 x 64, granule-swizzled
  const int tid = (int)threadIdx.x;
  const int lane = tid & 63;
  const int w = tid >> 6;   // 0..7
  const int wm = w >> 2;    // 0..1 : Q-row half
  const int wn = w & 3;     // 0..3 : S key-16-col / O d-64-col
  const int bx = (int)blockIdx.x;           // Q-tile
  const int by = (int)blockIdx.y;           // v*8 + b*4 + sp
  const int v = by >> 3, b = (by >> 2) & 1, sp = by & 3;
  const bf16* qb = qkv + (size_t)((v * 2 + b) * 4096) * 768;
  const bf16* vb = vT + (size_t)(v * 2 + b) * 1048576;
  attp += (size_t)by * 1048576;

  const int srow8 = lane >> 3;
  const int g8 = (lane & 4) | ((lane & 3) ^ ((lane >> 4) & 3));
  const int m15 = lane & 15, quad = lane >> 4;
  const int fq = quad ^ ((m15 >> 1) & 3);
  const int key0 = sp * 1024;

  // staging bases (chunk c = w of each 64x64 subtile)
  const bf16* gKb = qb + (size_t)(key0 + w * 8 + srow8) * 768 + 256 + g8 * 8;
  const bf16* gVb = vb + (size_t)(w * 8 + srow8) * 4096 + key0 + g8 * 8;

#define STAGE_K(T)                                               \
  do {                                                           \
    const bf16* gk_ = gKb + (size_t)(T) * 49152;                 \
    bf16* lk_ = Ks + w * 512;                                    \
    _Pragma("unroll") for (int j_ = 0; j_ < 4; ++j_)             \
        load_lds16(gk_ + j_ * 64, lk_ + j_ * 4096);              \
  } while (0)
#define STAGE_V(T)                                               \
  do {                                                           \
    const bf16* gv_ = gVb + (T) * 64;                            \
    bf16* lv_ = Vs + w * 512;                                    \
    _Pragma("unroll") for (int j_ = 0; j_ < 4; ++j_)             \
        load_lds16(gv_ + (size_t)j_ * 262144, lv_ + j_ * 4096);  \
  } while (0)

  STAGE_K(0);
  STAGE_V(0);

  // full Q fragments (compiler keeps/remats under the 128-VGPR cap;
  // re-loads are L1/L2 hits)
  bf16x8 qreg[4][8];
  const int qrow = bx * 128 + wm * 64 + m15;
#pragma unroll
  for (int mf = 0; mf < 4; ++mf)
#pragma unroll
    for (int ks = 0; ks < 8; ++ks)
      qreg[mf][ks] = *(const bf16x8*)(qb + (size_t)(qrow + mf * 16) * 768 +
                                      ks * 32 + quad * 8);

  f32x4 oacc[4][4];
#pragma unroll
  for (int mi = 0; mi < 4; ++mi)
#pragma unroll
    for (int ni = 0; ni < 4; ++ni) oacc[mi][ni] = (f32x4)(0.0f);
  float rs[4][4] = {};

  __syncthreads();  // drain tile-0 K/V DMAs + qreg loads
  __builtin_amdgcn_sched_barrier(0);

  const bf16* pKr = Ks + (wn * 16 + m15) * 64 + fq * 8;
  const bf16* pVr = Vs + wn * 4096 + m15 * 64 + fq * 8;
  // P write: row r = wm*64 + mf*16 + quad*4 + i, col k = wn*16 + m15;
  // granule p = (k>>3) ^ (2*((r>>2)&3)) = gP ^ (quad<<1)  (mf,i drop out)
  const int gP = wn * 2 + (m15 >> 3);
  bf16* pPw = Ps + (wm * 64 + quad * 4) * 64 + ((gP ^ (quad << 1)) << 3) +
              (m15 & 7);
  // P read: row r = wm*64 + m15 + mi*16 -> (r>>2)&3 = (m15>>2)&3
  const int xr = ((m15 >> 2) & 3) << 1;
  const bf16* pPr = Ps + (wm * 64 + m15) * 64;

  for (int t = 0; t < 16; ++t) {
    // ---- S phase: sacc[mf] = Q @ K^T, wave tile 64 rows x 16 keys
    f32x4 sacc[4];
#pragma unroll
    for (int mf = 0; mf < 4; ++mf) sacc[mf] = (f32x4)(0.0f);
#pragma unroll
    for (int ks = 0; ks < 8; ++ks) {
      const bf16x8 bvk =
          *(const bf16x8*)(pKr + (ks >> 1) * 4096 + (ks & 1) * 32);
#pragma unroll
      for (int mf = 0; mf < 4; ++mf)
        sacc[mf] = __builtin_amdgcn_mfma_f32_16x16x32_bf16(qreg[mf][ks], bvk,
                                                           sacc[mf], 0, 0, 0);
    }
    // ---- exp + P write (swizzled, conflict-free) + row-sum accumulate
#pragma unroll
    for (int mf = 0; mf < 4; ++mf)
#pragma unroll
      for (int i = 0; i < 4; ++i) {
        const float pe = exp2f(sacc[mf][i] * 0.09016844136f);  // /16 * log2 e
        rs[mf][i] += pe;
        pPw[mf * 1024 + i * 64] = __float2bfloat16(pe);
      }
    __builtin_amdgcn_sched_barrier(0);
    __syncthreads();  // mid: Ps visible; Ks(t) dead; V(t) DMA long drained
    __builtin_amdgcn_sched_barrier(0);
    if (t < 15) STAGE_K(t + 1);  // drains at end barrier, hidden under PV
    // ---- PV: oacc += P @ V ; wave tile 64 rows x 64 d
#pragma unroll
    for (int sub = 0; sub < 2; ++sub) {
      bf16x8 pa[4], bvv[4];
#pragma unroll
      for (int mi = 0; mi < 4; ++mi)
        pa[mi] = *(const bf16x8*)(pPr + mi * 1024 +
                                  ((((sub << 2) | quad) ^ xr) << 3));
#pragma unroll
      for (int ni = 0; ni < 4; ++ni)
        bvv[ni] = *(const bf16x8*)(pVr + ni * 1024 + sub * 32);
#pragma unroll
      for (int mi = 0; mi < 4; ++mi)
#pragma unroll
        for (int ni = 0; ni < 4; ++ni)
          oacc[mi][ni] = __builtin_amdgcn_mfma_f32_16x16x32_bf16(
              pa[mi], bvv[ni], oacc[mi][ni], 0, 0, 0);
    }
    __builtin_amdgcn_sched_barrier(0);
    __syncthreads();  // end: Vs(t)+Ps dead; K(t+1) DMA drained here
    __builtin_amdgcn_sched_barrier(0);
    if (t < 15) STAGE_V(t + 1);  // drains at next mid barrier, hidden under S
  }
#undef STAGE_K
#undef STAGE_V

  // ---- epilogue: O partials (bf16) + lpart channel (b*16 + sp*4 + wn)
  const int crow0 = bx * 128 + wm * 64 + quad * 4;
  const int ccol0 = wn * 64 + m15;
#pragma unroll
  for (int mi = 0; mi < 4; ++mi)
#pragma unroll
    for (int ni = 0; ni < 4; ++ni)
#pragma unroll
      for (int i = 0; i < 4; ++i)
        attp[(size_t)(crow0 + mi * 16 + i) * 256 + ccol0 + ni * 16] =
            __float2bfloat16(oacc[mi][ni][i]);
  float* lp = lpart + (size_t)v * 131072 +
              (size_t)(b * 16 + sp * 4 + wn) * 4096 + bx * 128 + wm * 64;
#pragma unroll
  for (int mf = 0; mf < 4; ++mf)
#pragma unroll
    for (int i = 0; i < 4; ++i) {
      float sv = rs[mf][i];
      sv += __shfl_xor(sv, 1);
      sv += __shfl_xor(sv, 2);
      sv += __shfl_xor(sv, 4);
      sv += __shfl_xor(sv, 8);
      if (m15 == 0) lp[mf * 16 + quad * 4 + i] = sv;
    }
}

// ---------------------------------------------------------------------------
// residual + LayerNorm, ALL 3 VIEWS in one dispatch (fused path).
// grid 24576: v = bid>>13, n = bid&8191. Emits 9 bf16 KAN basis channels.
// ---------------------------------------------------------------------------
__global__ __launch_bounds__(256) void resid_ln3(
    const bf16* __restrict__ attp, const float* __restrict__ lpart,
    const float* __restrict__ t0, const float* __restrict__ t1,
    const float* __restrict__ t2, const float* __restrict__ g0,
    const float* __restrict__ g1, const float* __restrict__ g2,
    const float* __restrict__ b0, const float* __restrict__ b1,
    const float* __restrict__ b2, bf16* __restrict__ basis) {
  __shared__ float red[4];
  __shared__ float sinvl;
  __shared__ __align__(16) bf16 st[2304];  // 256 elems x 9 channels
  const int bid = (int)blockIdx.x;
  const int vIdx = bid >> 13;
  const int n = bid & 8191;  // 0..8191 ; b = n>>12
  const int d = (int)threadIdx.x;
  const int b = n >> 12, r = n & 4095;
  const float* tok = vIdx == 0 ? t0 : (vIdx == 1 ? t1 : t2);
  const float* gamma = vIdx == 0 ? g0 : (vIdx == 1 ? g1 : g2);
  const float* beta = vIdx == 0 ? b0 : (vIdx == 1 ? b1 : b2);
  attp += (size_t)vIdx * 8388608;
  lpart += (size_t)vIdx * 131072;
  float ls = 0.f;
  if (d < 16) ls = lpart[((size_t)(b * 16 + d)) * 4096 + r];
  ls = wave_sum(ls);
  if (d == 0) sinvl = 1.0f / ls;
  const size_t abase = (size_t)(b * 4) * 1048576 + (size_t)r * 256 + d;
  const float asum = to_f32(attp[abase]) + to_f32(attp[abase + 1048576]) +
                     to_f32(attp[abase + 2097152]) +
                     to_f32(attp[abase + 3145728]);
  __syncthreads();
  const float y = asum * sinvl + tok[(size_t)n * 256 + d];
  float s = wave_sum(y);
  if ((d & 63) == 0) red[d >> 6] = s;
  __syncthreads();
  const float mu = (red[0] + red[1] + red[2] + red[3]) * (1.0f / 256.0f);
  __syncthreads();
  const float c = y - mu;
  float s2 = wave_sum(c * c);
  if ((d & 63) == 0) red[d >> 6] = s2;
  __syncthreads();
  const float var = (red[0] + red[1] + red[2] + red[3]) * (1.0f / 256.0f);
  const float rstd = rsqrtf(var + 1e-5f);
  const float val = c * rstd * gamma[d] + beta[d];
#pragma unroll
  for (int f = 0; f < 8; ++f)
    st[d * 9 + f] = __float2bfloat16(b3_cardinal(val, 5.5f - (float)f));
  st[d * 9 + 8] = __float2bfloat16(val / (1.0f + __expf(-val)));
  __syncthreads();
  float4* gb = (float4*)((char*)basis + (size_t)n * 13824 + vIdx * 4608);
  const float4* sb = (const float4*)st;
  gb[d] = sb[d];
  if (d < 32) gb[256 + d] = sb[256 + d];
}

// ---------------------------------------------------------------------------
// fallback resid_ln (single view, fp32 partials, writes x)
// ---------------------------------------------------------------------------
__global__ __launch_bounds__(256) void resid_ln_kernel(
    const float* __restrict__ attp, const float* __restrict__ lpart,
    const float* __restrict__ tok, const float* __restrict__ gamma,
    const float* __restrict__ beta, float* __restrict__ xout, int nch,
    int vIdx) {
  __shared__ float red[4];
  __shared__ float sinvl;
  const int n = (int)blockIdx.x;  // 0..8191 ; b = n>>12
  const int d = (int)threadIdx.x;
  const int b = n >> 12, r = n & 4095;
  float ls = 0.f;
  if (d < nch) ls = lpart[((size_t)(b * nch + d)) * 4096 + r];
  ls = wave_sum(ls);
  if (d == 0) sinvl = 1.0f / ls;
  const size_t abase = (size_t)(b * 4) * 1048576 + (size_t)r * 256 + d;
  const float asum = attp[abase] + attp[abase + 1048576] +
                     attp[abase + 2097152] + attp[abase + 3145728];
  __syncthreads();
  const float y = asum * sinvl + tok[(size_t)n * 256 + d];
  float s = wave_sum(y);
  if ((d & 63) == 0) red[d >> 6] = s;
  __syncthreads();
  const float mu = (red[0] + red[1] + red[2] + red[3]) * (1.0f / 256.0f);
  __syncthreads();
  const float c = y - mu;
  float s2 = wave_sum(c * c);
  if ((d & 63) == 0) red[d >> 6] = s2;
  __syncthreads();
  const float var = (red[0] + red[1] + red[2] + red[3]) * (1.0f / 256.0f);
  const float rstd = rsqrtf(var + 1e-5f);
  xout[(size_t)n * 768 + vIdx * 256 + d] = c * rstd * gamma[d] + beta[d];
}

// ---------------------------------------------------------------------------
// merged prep: blocks 0..255 = prep_w ; 256..1023 = prep_qkvw ;
// 1024..7167 = cast_tok3 (2048 blocks per view).
// ---------------------------------------------------------------------------
__global__ __launch_bounds__(256) void prep_all(
    const float* __restrict__ bw, const float* __restrict__ sw,
    const float* __restrict__ scaler, bf16* __restrict__ Wmat,
    const float* __restrict__ wq, const float* __restrict__ wk,
    const float* __restrict__ wv, const float* __restrict__ bq,
    const float* __restrict__ bk, const float* __restrict__ bv,
    bf16* __restrict__ wqkvb, float* __restrict__ bqkv,
    const float4* __restrict__ t0, const float4* __restrict__ t1,
    const float4* __restrict__ t2, bf16* __restrict__ tokb) {
  const int bid = (int)blockIdx.x;
  const int tid = (int)threadIdx.x;
  if (bid < 256) {
    const int o = bid;
    for (int ii = 0; ii < 3; ++ii) {
      const int i = ii * 256 + tid;
      const float s = scaler[(size_t)o * 768 + i];
      bf16* p = Wmat + (size_t)o * 6912 + i * 9;
      const float* swp = sw + ((size_t)o * 768 + i) * 8;
#pragma unroll
      for (int f = 0; f < 8; ++f) p[f] = __float2bfloat16(swp[f] * s);
      p[8] = __float2bfloat16(bw[(size_t)o * 768 + i]);
    }
  } else if (bid < 1024) {
    const int idx = (bid - 256) * 256 + tid;
    const int row = idx >> 8, col = idx & 255;
    const float* src = row < 256 ? wq : (row < 512 ? wk : wv);
    wqkvb[idx] = __float2bfloat16(src[((row & 255) << 8) + col]);
    if (idx < 768)
      bqkv[idx] =
          idx < 256 ? bq[idx] : (idx < 512 ? bk[idx - 256] : bv[idx - 512]);
  } else {
    const int f = bid - 1024;
    const int vv = f >> 11;
    const int idx = (f & 2047) * 256 + tid;
    const float4* src = vv == 0 ? t0 : (vv == 1 ? t1 : t2);
    const float4 val = src[idx];
    bf16* p = tokb + (size_t)vv * 2097152 + (size_t)idx * 4;
    p[0] = __float2bfloat16(val.x);
    p[1] = __float2bfloat16(val.y);
    p[2] = __float2bfloat16(val.z);
    p[3] = __float2bfloat16(val.w);
  }
}

// vT[z][d][s] = qkv[z*4096+s][512+d]
__global__ __launch_bounds__(256) void transpose_v(
    const bf16* __restrict__ qkv, bf16* __restrict__ vT) {
  __shared__ bf16 tle[64][65];
  const int s0 = blockIdx.x << 6, d0 = blockIdx.y << 6, z = blockIdx.z;
  const int tid = (int)threadIdx.x;
  const int c = tid & 63, rr = tid >> 6;
  for (int r = 0; r < 64; r += 4)
    tle[r + rr][c] = qkv[(size_t)(z * 4096 + s0 + r + rr) * 768 + 512 + d0 + c];
  __syncthreads();
  for (int r = 0; r < 64; r += 4)
    vT[(size_t)z * 1048576 + (size_t)(d0 + r + rr) * 4096 + s0 + c] =
        tle[c][r + rr];
}

// ---------------------------------------------------------------------------
// fallback basis: basis[n][i*9+f] from x (Cox-de-Boor, proven R6)
// ---------------------------------------------------------------------------
__global__ __launch_bounds__(256) void basis_kernel(
    const float* __restrict__ x, bf16* __restrict__ basis) {
  const int i = blockIdx.x * 256 + (int)threadIdx.x;  // 0..767
  const int n = blockIdx.y;
  const float xv = x[(size_t)n * 768 + i];
  float b[11];
#pragma unroll
  for (int m = 0; m < 11; ++m) {
    const float g0 = 0.4f * (float)(m - 3) - 1.0f;
    const float g1 = 0.4f * (float)(m - 2) - 1.0f;
    b[m] = (xv >= g0 && xv < g1) ? 1.0f : 0.0f;
  }
#pragma unroll
  for (int k = 1; k <= 3; ++k) {
    const float inv = 1.0f / (0.4f * (float)k);
#pragma unroll
    for (int m = 0; m + k < 11; ++m) {
      const float gm = 0.4f * (float)(m - 3) - 1.0f;
      const float gmk1 = 0.4f * (float)(m + k - 2) - 1.0f;
      b[m] = (xv - gm) * inv * b[m] + (gmk1 - xv) * inv * b[m + 1];
    }
  }
  bf16* p = basis + (size_t)n * 6912 + i * 9;
#pragma unroll
  for (int f = 0; f < 8; ++f) p[f] = __float2bfloat16(b[f]);
  p[8] = __float2bfloat16(xv / (1.0f + __expf(-xv)));
}

__global__ __launch_bounds__(256) void combine4_kernel(
    const float4* __restrict__ p, float4* __restrict__ out) {
  const int idx = blockIdx.x * 256 + (int)threadIdx.x;
  const float4 a = p[idx];
  const float4 b = p[idx + 524288];
  const float4 c = p[idx + 1048576];
  const float4 d = p[idx + 1572864];
  out[idx] =
      make_float4(a.x + b.x + c.x + d.x, a.y + b.y + c.y + d.y,
                  a.z + b.z + c.z + d.z, a.w + b.w + c.w + d.w);
}

// combine 6 bf16 partial slices (stride 2,097,152 elements) -> fp32 out
__global__ __launch_bounds__(256) void combine6b_kernel(
    const bf16* __restrict__ p, float4* __restrict__ out) {
  const int idx = blockIdx.x * 256 + (int)threadIdx.x;  // 0..524287
  float a0 = 0.f, a1 = 0.f, a2 = 0.f, a3 = 0.f;
#pragma unroll
  for (int j = 0; j < 6; ++j) {
    const bf16* q = p + (size_t)j * 2097152 + (size_t)idx * 4;
    a0 += __bfloat162float(q[0]);
    a1 += __bfloat162float(q[1]);
    a2 += __bfloat162float(q[2]);
    a3 += __bfloat162float(q[3]);
  }
  out[idx] = make_float4(a0, a1, a2, a3);
}

// ---------------------------------------------------------------------------
extern "C" void kernel_launch(void* const* d_in, const int* in_sizes, int n_in,
                              void* d_out, int out_size, void* d_ws,
                              size_t ws_size, hipStream_t stream) {
  const float* tok[3] = {(const float*)d_in[0], (const float*)d_in[1],
                         (const float*)d_in[2]};
  const float* wq = (const float*)d_in[3];
  const float* bq = (const float*)d_in[4];
  const float* wk = (const float*)d_in[5];
  const float* bk = (const float*)d_in[6];
  const float* wv = (const float*)d_in[7];
  const float* bv = (const float*)d_in[8];
  // d_in[9] view_emb unused (softmax-invariant)
  const float* lng[3] = {(const float*)d_in[10], (const float*)d_in[12],
                         (const float*)d_in[14]};
  const float* lnb[3] = {(const float*)d_in[11], (const float*)d_in[13],
                         (const float*)d_in[15]};
  const float* bw = (const float*)d_in[16];
  const float* sw = (const float*)d_in[17];
  const float* scaler = (const float*)d_in[18];

  // fused layout (R13, total 169,085,952 B <= known-safe 194,776,064):
  //   basis @0 (113,246,208) -- written by resid_ln3 AFTER attention; until
  //     then sub-aliased: tokb @0 (12.58M) | qkv @12,582,912 (37.75M) |
  //     vT @50,331,648 (12.58M, ends 62,914,560)
  //   attb (bf16 partials, 24 x 2,097,152 B) @113,246,208 -> 163,577,856
  //   lpart_f @163,577,856 (1.57M) -> 165,150,720
  //   Wmat @165,150,720 (3.54M) | wqkvb @168,689,664 | bqkv @169,082,880
  //   poutb (KAN z=6, bf16, 25.2MB) aliases attb (dead after resid_ln3)
  // fallback (unchanged): Pb @62,914,560 | lpart @130,023,424 |
  //   attp @132,120,576 | x @165,675,008 | basis aliases [0,..) |
  //   Wmat @190,840,832 | pout aliases attp.
  const bool fused = ws_size >= 169085952ull;
  char* w8 = (char*)d_ws;
  bf16* tokb = (bf16*)(w8 + 0);
  bf16* qkv = (bf16*)(w8 + 12582912);
  bf16* vT = (bf16*)(w8 + 50331648);
  float* x;
  bf16* basis;
  bf16* Wmat;
  // fallback pointers
  bf16* Pb = (bf16*)(w8 + 62914560);
  float* lpart = (float*)(w8 + 130023424);
  float* attp = (float*)(w8 + 132120576);
  float* pout = attp;  // fallback KAN partials (fp32)
  // fused pointers
  bf16* attb = (bf16*)(w8 + 113246208);
  float* lpart_f = (float*)(w8 + 163577856);
  bf16* poutb = (bf16*)(w8 + 113246208);  // bf16 KAN partials, attb dead
  if (fused) {
    x = nullptr;
    basis = (bf16*)(w8 + 0);
    Wmat = (bf16*)(w8 + 165150720);
  } else {
    x = (float*)(w8 + 165675008);
    basis = (bf16*)(w8 + 0);
    Wmat = (bf16*)(w8 + 190840832);
  }
  bf16* wqkvb = (bf16*)((char*)Wmat + 3538944);
  float* bqkv = (float*)((char*)wqkvb + 393216);

  prep_all<<<7168, 256, 0, stream>>>(bw, sw, scaler, Wmat, wq, wk, wv, bq, bk,
                                     bv, wqkvb, bqkv, (const float4*)tok[0],
                                     (const float4*)tok[1],
                                     (const float4*)tok[2], tokb);

  // QKV all views: [24576,256] @ [768,256]^T + bias -> qkv bf16
  mfma_gemm_bt<bf16, false><<<dim3(6, 192, 1), 256, 0, stream>>>(
      tokb, wqkvb, bqkv, qkv, nullptr, 256, 256, 256, 768, 1, 0, 0, 0, 0, 0,
      0, 1.0f);
  transpose_v<<<dim3(64, 4, 6), 256, 0, stream>>>(qkv, vT);

  if (fused) {
    // fused flash attention: all views/batches/splits in one dispatch
    fused_attn<<<dim3(32, 24), 512, 0, stream>>>(qkv, vT, attb, lpart_f);
    // residual + LN + basis, all 3 views in one dispatch
    resid_ln3<<<24576, 256, 0, stream>>>(attb, lpart_f, tok[0], tok[1],
                                         tok[2], lng[0], lng[1], lng[2],
                                         lnb[0], lnb[1], lnb[2], basis);
    // KAN split-K=6 (z=6, 768 blocks = 3/CU), bf16 partials
    mfma_gemm_bt<bf16, false><<<dim3(2, 64, 6), 256, 0, stream>>>(
        basis, Wmat, nullptr, poutb, nullptr, 1152, 6912, 6912, 256, 3, 0,
        1152, 0, 1152, 2097152, 0, 1.0f);
    combine6b_kernel<<<2048, 256, 0, stream>>>(poutb, (float4*)d_out);
  } else {
    for (int v = 0; v < 3; ++v) {
      const bf16* qb = qkv + (size_t)(2 * v) * 4096 * 768;
      // scores both batches (z=2): P = exp(q@k^T/16) bf16 + lpart partials
      mfma_gemm_bt<bf16, true><<<dim3(32, 32, 2), 256, 0, stream>>>(
          qb, qb + 256, nullptr, Pb, lpart, 256, 768, 768, 4096, 1, 0,
          3145728, 0, 3145728, 16777216, 262144, 0.0625f);
      // PV split-K=4 x batch (z=8): attp[z] = P-slice @ vT-slice^T
      mfma_gemm_bt<float, false><<<dim3(2, 32, 8), 256, 0, stream>>>(
          Pb, vT + (size_t)(2 * v) * 1048576, nullptr, attp, nullptr, 1024,
          4096, 4096, 256, 2, 16777216, 1024, 1048576, 1024, 1048576, 0, 1.0f);
      resid_ln_kernel<<<8192, 256, 0, stream>>>(attp, lpart, tok[v], lng[v],
                                                lnb[v], x, 64, v);
    }
    basis_kernel<<<dim3(3, 8192), 256, 0, stream>>>(x, basis);
    mfma_gemm_bt<float, false><<<dim3(2, 64, 4), 256, 0, stream>>>(
        basis, Wmat, nullptr, pout, nullptr, 1728, 6912, 6912, 256, 2, 0,
        1728, 0, 1728, 2097152, 0, 1.0f);
    combine4_kernel<<<2048, 256, 0, stream>>>((const float4*)pout,
                                              (float4*)d_out);
  }
}

// Round 15
// 374.387 us; speedup vs baseline: 1.1916x; 1.0084x over previous
//
#include <hip/hip_runtime.h>
#include <hip/hip_bf16.h>
#include <math.h>

// ---------------------------------------------------------------------------
// B=2, S=4096, D=256, IN=768, N_BASIS=8, spline grid h=0.4
// view_emb adds a row-constant to pre-softmax scores -> cancelled -> unused.
// Softmax without max-subtraction: |q.k|/16 <= ~1.7 -> online softmax LINEAR.
// R25: occupancy law resolved: blocks/CU = arg*4/(waves/block).
// (512,2)=1 blk (22% everywhere), (512,4)=2 blks (R16 34%) but VGPR cap
// 256/arg=64 spilled. Escape: 4-WAVE blocks with (256,2) -> 2 blocks/CU at
// VGPR cap 128 (proven spill-free R17/R23). fused_attn rebuilt: 256 thr =
// 4 waves (2wm x 2wn), Q-tile 64 rows, grid (64,24). Same K/V/Ps layouts
// (72KB -> 2x72=144<=160KB). Per-wave MFMA identical (32 S + 32 PV/tile).
// P-write banks re-verified 2/bank free; P-read/bvv uniform-8. lpart -> 8
// ch/batch. R24 kept: bf16 KAN partials + combine6b, resid_ln3 one-dispatch,
// prep_all. R13 layout; R11 sched_barrier pins.
// ---------------------------------------------------------------------------

typedef __hip_bfloat16 bf16;
using bf16x8 = __attribute__((ext_vector_type(8))) __bf16;
using f32x4  = __attribute__((ext_vector_type(4))) float;

__device__ __forceinline__ void load_lds16(const void* g, void* l) {
  __builtin_amdgcn_global_load_lds((__attribute__((address_space(1))) void*)g,
                                   (__attribute__((address_space(3))) void*)l,
                                   16, 0, 0);
}

__device__ __forceinline__ float wave_sum(float v) {
#pragma unroll
  for (int o = 32; o > 0; o >>= 1) v += __shfl_down(v, o, 64);
  return v;
}

__device__ __forceinline__ float to_f32(float v) { return v; }
__device__ __forceinline__ float to_f32(bf16 v) { return __bfloat162float(v); }

// closed-form cardinal cubic B-spline segment (validated R7)
__device__ __forceinline__ float b3_cardinal(float x, float tofs) {
  const float t = fmaf(x, 2.5f, tofs);
  const float tc = fminf(fmaxf(t, 0.0f), 4.0f);
  const float p2 = fmaxf(tc - 1.0f, 0.0f);
  const float p3 = fmaxf(tc - 2.0f, 0.0f);
  const float p4 = fmaxf(tc - 3.0f, 0.0f);
  return (tc * tc * tc - 4.0f * p2 * p2 * p2 + 6.0f * p3 * p3 * p3 -
          4.0f * p4 * p4 * p4) * (1.0f / 6.0f);
}

// ---------------------------------------------------------------------------
// bf16 MFMA GEMM, BT form, BK=64 (proven): used by QKV + KAN (+ fallback).
// ---------------------------------------------------------------------------
template <typename OutT, bool EXP>
__global__ __launch_bounds__(256) void mfma_gemm_bt(
    const bf16* __restrict__ A, const bf16* __restrict__ B,
    const float* __restrict__ bias, OutT* __restrict__ C,
    float* __restrict__ lpart, int K, int lda, int ldb, int ldc, int zshift,
    size_t zAh, size_t zAl, size_t zBh, size_t zBl, size_t zC, size_t zL,
    float scale) {
  __shared__ __align__(16) bf16 As[8192];  // 128 x 64
  __shared__ __align__(16) bf16 Bs[8192];
  const int tid = (int)threadIdx.x;
  const int lane = tid & 63;
  const int w = tid >> 6;
  const int m0 = (int)blockIdx.y << 7;
  const int n0 = (int)blockIdx.x << 7;
  const size_t z = blockIdx.z;
  const size_t zlo = z & (((size_t)1 << zshift) - 1);
  A += (z >> zshift) * zAh + zlo * zAl;
  B += (z >> zshift) * zBh + zlo * zBl;
  C += z * zC;
  if (EXP) lpart += z * zL;

  // staging geometry
  const int srow8 = lane >> 3;  // row within 8-row chunk
  const int g8 = (lane & 4) | ((lane & 3) ^ ((lane >> 4) & 3));
  const bf16* gA[4];
  const bf16* gB[4];
  bf16* lA[4];
  bf16* lB[4];
#pragma unroll
  for (int j = 0; j < 4; ++j) {
    const int c = w + 4 * j;
    gA[j] = A + (size_t)(m0 + c * 8 + srow8) * lda + g8 * 8;
    gB[j] = B + (size_t)(n0 + c * 8 + srow8) * ldb + g8 * 8;
    lA[j] = As + c * 512;
    lB[j] = Bs + c * 512;
  }

  // fragment geometry
  const int m15 = lane & 15, quad = lane >> 4;
  const int fq = quad ^ ((m15 >> 1) & 3);
  const bf16* pA = As + (size_t)(((w >> 1) << 6) + m15) * 64 + fq * 8;
  const bf16* pB = Bs + (size_t)(((w & 1) << 6) + m15) * 64 + fq * 8;

  f32x4 acc[4][4];
#pragma unroll
  for (int mi = 0; mi < 4; ++mi)
#pragma unroll
    for (int ni = 0; ni < 4; ++ni) acc[mi][ni] = (f32x4)(0.0f);

  for (int k0 = 0; k0 < K; k0 += 64) {
#pragma unroll
    for (int j = 0; j < 4; ++j) {
      load_lds16(gA[j], lA[j]);
      load_lds16(gB[j], lB[j]);
      gA[j] += 64;
      gB[j] += 64;
    }
    __syncthreads();
    __builtin_amdgcn_sched_barrier(0);  // ds_reads must not hoist above barrier
    bf16x8 av[4][2], bv[4][2];
#pragma unroll
    for (int mi = 0; mi < 4; ++mi)
#pragma unroll
      for (int sub = 0; sub < 2; ++sub) {
        av[mi][sub] = *(const bf16x8*)(pA + mi * 1024 + sub * 32);
        bv[mi][sub] = *(const bf16x8*)(pB + mi * 1024 + sub * 32);
      }
#pragma unroll
    for (int sub = 0; sub < 2; ++sub)
#pragma unroll
      for (int mi = 0; mi < 4; ++mi)
#pragma unroll
        for (int ni = 0; ni < 4; ++ni)
          acc[mi][ni] = __builtin_amdgcn_mfma_f32_16x16x32_bf16(
              av[mi][sub], bv[ni][sub], acc[mi][ni], 0, 0, 0);
    __builtin_amdgcn_sched_barrier(0);  // reads/MFMAs must not sink below
    __syncthreads();
    __builtin_amdgcn_sched_barrier(0);  // next-iter LDS-DMA must not hoist
  }

  const int crow = m0 + ((w >> 1) << 6) + quad * 4;
  const int ccol = n0 + ((w & 1) << 6) + m15;
  float rs[4][4] = {};
#pragma unroll
  for (int ni = 0; ni < 4; ++ni) {
    const int col = ccol + ni * 16;
    const float bb = bias ? bias[col] : 0.0f;
#pragma unroll
    for (int mi = 0; mi < 4; ++mi) {
#pragma unroll
      for (int i = 0; i < 4; ++i) {
        const int row = crow + mi * 16 + i;
        float v = acc[mi][ni][i] * scale + bb;
        if constexpr (EXP) {
          v = __expf(v);
          rs[mi][i] += v;
        }
        if constexpr (sizeof(OutT) == 2)
          C[(size_t)row * ldc + col] = __float2bfloat16(v);
        else
          C[(size_t)row * ldc + col] = v;
      }
    }
  }
  if constexpr (EXP) {
    const int ch = ((int)blockIdx.x << 1) | (w & 1);
#pragma unroll
    for (int mi = 0; mi < 4; ++mi)
#pragma unroll
      for (int i = 0; i < 4; ++i) {
        float sv = rs[mi][i];
        sv += __shfl_xor(sv, 1);
        sv += __shfl_xor(sv, 2);
        sv += __shfl_xor(sv, 4);
        sv += __shfl_xor(sv, 8);
        if (m15 == 0)
          lpart[(size_t)ch * 4096 + crow + mi * 16 + i] = sv;
      }
  }
}

// ---------------------------------------------------------------------------
// R25 fused flash attention: 256 thr = 4 waves (2 wm x 2 wn), Q-tile 64
// rows, 16 tiles x 64 keys. grid = (64 Qtiles, 24 = v*8 + b*4 + sp).
// launch_bounds(256,2): 2 blocks/CU (k = 2*4/4), VGPR cap 128 (proven).
// LDS 72KB: Ks 4x[64key][64k] 32K + Vs 4x[64d][64key] 32K + Ps[64][64] 8K.
// Per wave: S = 32 rows x 32 keys (sacc[2][2], 8 ks); PV = 32 rows x 128 d
// (oacc[2][8]). Split staging: K(t+1) after mid barrier (drains under PV),
// V(t+1) after end barrier (drains under next S). Ps granule swizzle
// p = g ^ (quad<<1): writes 2 lanes/bank (free), reads uniform 8/bank.
// Outputs: attp bf16 partials + lpart 8 ch/(batch,view).
// ---------------------------------------------------------------------------
__global__ __launch_bounds__(256, 2) void fused_attn(
    const bf16* __restrict__ qkv, const bf16* __restrict__ vT,
    bf16* __restrict__ attp, float* __restrict__ lpart) {
  __shared__ __align__(16) bf16 Ks[16384];  // 4 subtiles 64(keys)x64(k)
  __shared__ __align__(16) bf16 Vs[16384];  // 4 rowgroups 64(d)x64(key)
  __shared__ __align__(16) bf16 Ps[4096];   // 64 x 64, granule-swizzled
  const int tid = (int)threadIdx.x;
  const int lane = tid & 63;
  const int w = tid >> 6;   // 0..3
  const int wm = w >> 1;    // 0..1 : Q-row 32-half
  const int wn = w & 1;     // 0..1 : S key-32-half / O d-128-half
  const int bx = (int)blockIdx.x;           // Q-tile (64 rows)
  const int by = (int)blockIdx.y;           // v*8 + b*4 + sp
  const int v = by >> 3, b = (by >> 2) & 1, sp = by & 3;
  const bf16* qb = qkv + (size_t)((v * 2 + b) * 4096) * 768;
  const bf16* vb = vT + (size_t)(v * 2 + b) * 1048576;
  attp += (size_t)by * 1048576;

  const int srow8 = lane >> 3;
  const int g8 = (lane & 4) | ((lane & 3) ^ ((lane >> 4) & 3));
  const int m15 = lane & 15, quad = lane >> 4;
  const int fq = quad ^ ((m15 >> 1) & 3);
  const int key0 = sp * 1024;

  // staging bases: wave handles row-chunks w and w+4 of each 64x64 subtile
  const bf16* gKb = qb + (size_t)(key0 + w * 8 + srow8) * 768 + 256 + g8 * 8;
  const bf16* gVb = vb + (size_t)(w * 8 + srow8) * 4096 + key0 + g8 * 8;

#define STAGE_K(T)                                                    \
  do {                                                                \
    _Pragma("unroll") for (int h_ = 0; h_ < 2; ++h_) {                \
      const bf16* gk_ = gKb + (size_t)(T) * 49152 + h_ * 24576;       \
      bf16* lk_ = Ks + (w + h_ * 4) * 512;                            \
      _Pragma("unroll") for (int j_ = 0; j_ < 4; ++j_)                \
          load_lds16(gk_ + j_ * 64, lk_ + j_ * 4096);                 \
    }                                                                 \
  } while (0)
#define STAGE_V(T)                                                    \
  do {                                                                \
    _Pragma("unroll") for (int h_ = 0; h_ < 2; ++h_) {                \
      const bf16* gv_ = gVb + (T) * 64 + h_ * 131072;                 \
      bf16* lv_ = Vs + (w + h_ * 4) * 512;                            \
      _Pragma("unroll") for (int j_ = 0; j_ < 4; ++j_)                \
          load_lds16(gv_ + (size_t)j_ * 262144, lv_ + j_ * 4096);     \
    }                                                                 \
  } while (0)

  STAGE_K(0);
  STAGE_V(0);

  // Q fragments (compiler keeps/remats under the 128-VGPR cap; L1/L2 hits)
  bf16x8 qreg[2][8];
  const int qrow = bx * 64 + wm * 32 + m15;
#pragma unroll
  for (int mf = 0; mf < 2; ++mf)
#pragma unroll
    for (int ks = 0; ks < 8; ++ks)
      qreg[mf][ks] = *(const bf16x8*)(qb + (size_t)(qrow + mf * 16) * 768 +
                                      ks * 32 + quad * 8);

  f32x4 oacc[2][8];
#pragma unroll
  for (int mi = 0; mi < 2; ++mi)
#pragma unroll
    for (int ni = 0; ni < 8; ++ni) oacc[mi][ni] = (f32x4)(0.0f);
  float rs[2][4] = {};

  __syncthreads();  // drain tile-0 K/V DMAs + qreg loads
  __builtin_amdgcn_sched_barrier(0);

  // S: key rows wn*32 + kf*16 + m15 (kf adds 1024 elements)
  const bf16* pKr = Ks + (wn * 32 + m15) * 64 + fq * 8;
  // PV B-operand: d-col = wn*128 + ni*16 + m15
  const bf16* pVr = Vs + wn * 8192 + m15 * 64 + fq * 8;
  // P write: row r = wm*32 + mf*16 + quad*4 + i ((r>>2)&3 = quad),
  // col k = wn*32 + kf*16 + m15; granule g = wn*4 + kf*2 + (m15>>3);
  // swizzled p = g ^ (quad<<1).
  const int gP0 = wn * 4 + (m15 >> 3);
  bf16* pPw0 = Ps + (wm * 32 + quad * 4) * 64 + ((gP0 ^ (quad << 1)) << 3) +
               (m15 & 7);
  bf16* pPw1 = Ps + (wm * 32 + quad * 4) * 64 +
               (((gP0 + 2) ^ (quad << 1)) << 3) + (m15 & 7);
  // P read: row r = wm*32 + mi*16 + m15 -> (r>>2)&3 = (m15>>2)&3
  const int xr = ((m15 >> 2) & 3) << 1;
  const bf16* pPr = Ps + (wm * 32 + m15) * 64;

  for (int t = 0; t < 16; ++t) {
    // ---- S phase: wave tile 32 rows x 32 keys, sacc[mf][kf]
    f32x4 sacc[2][2];
#pragma unroll
    for (int mf = 0; mf < 2; ++mf)
#pragma unroll
      for (int kf = 0; kf < 2; ++kf) sacc[mf][kf] = (f32x4)(0.0f);
#pragma unroll
    for (int ks = 0; ks < 8; ++ks) {
      const bf16x8 bvk0 =
          *(const bf16x8*)(pKr + (ks >> 1) * 4096 + (ks & 1) * 32);
      const bf16x8 bvk1 =
          *(const bf16x8*)(pKr + 1024 + (ks >> 1) * 4096 + (ks & 1) * 32);
#pragma unroll
      for (int mf = 0; mf < 2; ++mf) {
        sacc[mf][0] = __builtin_amdgcn_mfma_f32_16x16x32_bf16(
            qreg[mf][ks], bvk0, sacc[mf][0], 0, 0, 0);
        sacc[mf][1] = __builtin_amdgcn_mfma_f32_16x16x32_bf16(
            qreg[mf][ks], bvk1, sacc[mf][1], 0, 0, 0);
      }
    }
    // ---- exp + P write (swizzled, conflict-free) + row-sum accumulate
#pragma unroll
    for (int mf = 0; mf < 2; ++mf)
#pragma unroll
      for (int i = 0; i < 4; ++i) {
        const float pe0 = exp2f(sacc[mf][0][i] * 0.09016844136f);
        const float pe1 = exp2f(sacc[mf][1][i] * 0.09016844136f);
        rs[mf][i] += pe0 + pe1;
        pPw0[mf * 1024 + i * 64] = __float2bfloat16(pe0);
        pPw1[mf * 1024 + i * 64] = __float2bfloat16(pe1);
      }
    __builtin_amdgcn_sched_barrier(0);
    __syncthreads();  // mid: Ps visible; Ks(t) dead; V(t) DMA long drained
    __builtin_amdgcn_sched_barrier(0);
    if (t < 15) STAGE_K(t + 1);  // drains at end barrier, hidden under PV
    // ---- PV: wave tile 32 rows x 128 d, oacc[mi][ni]
#pragma unroll
    for (int sub = 0; sub < 2; ++sub) {
      bf16x8 pa[2], bvv[8];
#pragma unroll
      for (int mi = 0; mi < 2; ++mi)
        pa[mi] = *(const bf16x8*)(pPr + mi * 1024 +
                                  ((((sub << 2) | quad) ^ xr) << 3));
#pragma unroll
      for (int ni = 0; ni < 8; ++ni)
        bvv[ni] = *(const bf16x8*)(pVr + (ni >> 2) * 4096 + (ni & 3) * 1024 +
                                   sub * 32);
#pragma unroll
      for (int mi = 0; mi < 2; ++mi)
#pragma unroll
        for (int ni = 0; ni < 8; ++ni)
          oacc[mi][ni] = __builtin_amdgcn_mfma_f32_16x16x32_bf16(
              pa[mi], bvv[ni], oacc[mi][ni], 0, 0, 0);
    }
    __builtin_amdgcn_sched_barrier(0);
    __syncthreads();  // end: Vs(t)+Ps dead; K(t+1) DMA drained here
    __builtin_amdgcn_sched_barrier(0);
    if (t < 15) STAGE_V(t + 1);  // drains at next mid barrier, hidden under S
  }
#undef STAGE_K
#undef STAGE_V

  // ---- epilogue: O partials (bf16) + lpart channel (b*8 + sp*2 + wn)
  const int crow0 = bx * 64 + wm * 32 + quad * 4;
  const int ccol0 = wn * 128 + m15;
#pragma unroll
  for (int mi = 0; mi < 2; ++mi)
#pragma unroll
    for (int ni = 0; ni < 8; ++ni)
#pragma unroll
      for (int i = 0; i < 4; ++i)
        attp[(size_t)(crow0 + mi * 16 + i) * 256 + ccol0 + ni * 16] =
            __float2bfloat16(oacc[mi][ni][i]);
  float* lp = lpart + (size_t)v * 65536 +
              (size_t)(b * 8 + sp * 2 + wn) * 4096 + bx * 64 + wm * 32;
#pragma unroll
  for (int mf = 0; mf < 2; ++mf)
#pragma unroll
    for (int i = 0; i < 4; ++i) {
      float sv = rs[mf][i];
      sv += __shfl_xor(sv, 1);
      sv += __shfl_xor(sv, 2);
      sv += __shfl_xor(sv, 4);
      sv += __shfl_xor(sv, 8);
      if (m15 == 0) lp[mf * 16 + quad * 4 + i] = sv;
    }
}

// ---------------------------------------------------------------------------
// residual + LayerNorm, ALL 3 VIEWS in one dispatch (fused path).
// grid 24576: v = bid>>13, n = bid&8191. Emits 9 bf16 KAN basis channels.
// ---------------------------------------------------------------------------
__global__ __launch_bounds__(256) void resid_ln3(
    const bf16* __restrict__ attp, const float* __restrict__ lpart,
    const float* __restrict__ t0, const float* __restrict__ t1,
    const float* __restrict__ t2, const float* __restrict__ g0,
    const float* __restrict__ g1, const float* __restrict__ g2,
    const float* __restrict__ b0, const float* __restrict__ b1,
    const float* __restrict__ b2, bf16* __restrict__ basis) {
  __shared__ float red[4];
  __shared__ float sinvl;
  __shared__ __align__(16) bf16 st[2304];  // 256 elems x 9 channels
  const int bid = (int)blockIdx.x;
  const int vIdx = bid >> 13;
  const int n = bid & 8191;  // 0..8191 ; b = n>>12
  const int d = (int)threadIdx.x;
  const int b = n >> 12, r = n & 4095;
  const float* tok = vIdx == 0 ? t0 : (vIdx == 1 ? t1 : t2);
  const float* gamma = vIdx == 0 ? g0 : (vIdx == 1 ? g1 : g2);
  const float* beta = vIdx == 0 ? b0 : (vIdx == 1 ? b1 : b2);
  attp += (size_t)vIdx * 8388608;
  lpart += (size_t)vIdx * 65536;
  float ls = 0.f;
  if (d < 8) ls = lpart[((size_t)(b * 8 + d)) * 4096 + r];
  ls = wave_sum(ls);
  if (d == 0) sinvl = 1.0f / ls;
  const size_t abase = (size_t)(b * 4) * 1048576 + (size_t)r * 256 + d;
  const float asum = to_f32(attp[abase]) + to_f32(attp[abase + 1048576]) +
                     to_f32(attp[abase + 2097152]) +
                     to_f32(attp[abase + 3145728]);
  __syncthreads();
  const float y = asum * sinvl + tok[(size_t)n * 256 + d];
  float s = wave_sum(y);
  if ((d & 63) == 0) red[d >> 6] = s;
  __syncthreads();
  const float mu = (red[0] + red[1] + red[2] + red[3]) * (1.0f / 256.0f);
  __syncthreads();
  const float c = y - mu;
  float s2 = wave_sum(c * c);
  if ((d & 63) == 0) red[d >> 6] = s2;
  __syncthreads();
  const float var = (red[0] + red[1] + red[2] + red[3]) * (1.0f / 256.0f);
  const float rstd = rsqrtf(var + 1e-5f);
  const float val = c * rstd * gamma[d] + beta[d];
#pragma unroll
  for (int f = 0; f < 8; ++f)
    st[d * 9 + f] = __float2bfloat16(b3_cardinal(val, 5.5f - (float)f));
  st[d * 9 + 8] = __float2bfloat16(val / (1.0f + __expf(-val)));
  __syncthreads();
  float4* gb = (float4*)((char*)basis + (size_t)n * 13824 + vIdx * 4608);
  const float4* sb = (const float4*)st;
  gb[d] = sb[d];
  if (d < 32) gb[256 + d] = sb[256 + d];
}

// ---------------------------------------------------------------------------
// fallback resid_ln (single view, fp32 partials, writes x)
// ---------------------------------------------------------------------------
__global__ __launch_bounds__(256) void resid_ln_kernel(
    const float* __restrict__ attp, const float* __restrict__ lpart,
    const float* __restrict__ tok, const float* __restrict__ gamma,
    const float* __restrict__ beta, float* __restrict__ xout, int nch,
    int vIdx) {
  __shared__ float red[4];
  __shared__ float sinvl;
  const int n = (int)blockIdx.x;  // 0..8191 ; b = n>>12
  const int d = (int)threadIdx.x;
  const int b = n >> 12, r = n & 4095;
  float ls = 0.f;
  if (d < nch) ls = lpart[((size_t)(b * nch + d)) * 4096 + r];
  ls = wave_sum(ls);
  if (d == 0) sinvl = 1.0f / ls;
  const size_t abase = (size_t)(b * 4) * 1048576 + (size_t)r * 256 + d;
  const float asum = attp[abase] + attp[abase + 1048576] +
                     attp[abase + 2097152] + attp[abase + 3145728];
  __syncthreads();
  const float y = asum * sinvl + tok[(size_t)n * 256 + d];
  float s = wave_sum(y);
  if ((d & 63) == 0) red[d >> 6] = s;
  __syncthreads();
  const float mu = (red[0] + red[1] + red[2] + red[3]) * (1.0f / 256.0f);
  __syncthreads();
  const float c = y - mu;
  float s2 = wave_sum(c * c);
  if ((d & 63) == 0) red[d >> 6] = s2;
  __syncthreads();
  const float var = (red[0] + red[1] + red[2] + red[3]) * (1.0f / 256.0f);
  const float rstd = rsqrtf(var + 1e-5f);
  xout[(size_t)n * 768 + vIdx * 256 + d] = c * rstd * gamma[d] + beta[d];
}

// ---------------------------------------------------------------------------
// merged prep: blocks 0..255 = prep_w ; 256..1023 = prep_qkvw ;
// 1024..7167 = cast_tok3 (2048 blocks per view).
// ---------------------------------------------------------------------------
__global__ __launch_bounds__(256) void prep_all(
    const float* __restrict__ bw, const float* __restrict__ sw,
    const float* __restrict__ scaler, bf16* __restrict__ Wmat,
    const float* __restrict__ wq, const float* __restrict__ wk,
    const float* __restrict__ wv, const float* __restrict__ bq,
    const float* __restrict__ bk, const float* __restrict__ bv,
    bf16* __restrict__ wqkvb, float* __restrict__ bqkv,
    const float4* __restrict__ t0, const float4* __restrict__ t1,
    const float4* __restrict__ t2, bf16* __restrict__ tokb) {
  const int bid = (int)blockIdx.x;
  const int tid = (int)threadIdx.x;
  if (bid < 256) {
    const int o = bid;
    for (int ii = 0; ii < 3; ++ii) {
      const int i = ii * 256 + tid;
      const float s = scaler[(size_t)o * 768 + i];
      bf16* p = Wmat + (size_t)o * 6912 + i * 9;
      const float* swp = sw + ((size_t)o * 768 + i) * 8;
#pragma unroll
      for (int f = 0; f < 8; ++f) p[f] = __float2bfloat16(swp[f] * s);
      p[8] = __float2bfloat16(bw[(size_t)o * 768 + i]);
    }
  } else if (bid < 1024) {
    const int idx = (bid - 256) * 256 + tid;
    const int row = idx >> 8, col = idx & 255;
    const float* src = row < 256 ? wq : (row < 512 ? wk : wv);
    wqkvb[idx] = __float2bfloat16(src[((row & 255) << 8) + col]);
    if (idx < 768)
      bqkv[idx] =
          idx < 256 ? bq[idx] : (idx < 512 ? bk[idx - 256] : bv[idx - 512]);
  } else {
    const int f = bid - 1024;
    const int vv = f >> 11;
    const int idx = (f & 2047) * 256 + tid;
    const float4* src = vv == 0 ? t0 : (vv == 1 ? t1 : t2);
    const float4 val = src[idx];
    bf16* p = tokb + (size_t)vv * 2097152 + (size_t)idx * 4;
    p[0] = __float2bfloat16(val.x);
    p[1] = __float2bfloat16(val.y);
    p[2] = __float2bfloat16(val.z);
    p[3] = __float2bfloat16(val.w);
  }
}

// vT[z][d][s] = qkv[z*4096+s][512+d]
__global__ __launch_bounds__(256) void transpose_v(
    const bf16* __restrict__ qkv, bf16* __restrict__ vT) {
  __shared__ bf16 tle[64][65];
  const int s0 = blockIdx.x << 6, d0 = blockIdx.y << 6, z = blockIdx.z;
  const int tid = (int)threadIdx.x;
  const int c = tid & 63, rr = tid >> 6;
  for (int r = 0; r < 64; r += 4)
    tle[r + rr][c] = qkv[(size_t)(z * 4096 + s0 + r + rr) * 768 + 512 + d0 + c];
  __syncthreads();
  for (int r = 0; r < 64; r += 4)
    vT[(size_t)z * 1048576 + (size_t)(d0 + r + rr) * 4096 + s0 + c] =
        tle[c][r + rr];
}

// ---------------------------------------------------------------------------
// fallback basis: basis[n][i*9+f] from x (Cox-de-Boor, proven R6)
// ---------------------------------------------------------------------------
__global__ __launch_bounds__(256) void basis_kernel(
    const float* __restrict__ x, bf16* __restrict__ basis) {
  const int i = blockIdx.x * 256 + (int)threadIdx.x;  // 0..767
  const int n = blockIdx.y;
  const float xv = x[(size_t)n * 768 + i];
  float b[11];
#pragma unroll
  for (int m = 0; m < 11; ++m) {
    const float g0 = 0.4f * (float)(m - 3) - 1.0f;
    const float g1 = 0.4f * (float)(m - 2) - 1.0f;
    b[m] = (xv >= g0 && xv < g1) ? 1.0f : 0.0f;
  }
#pragma unroll
  for (int k = 1; k <= 3; ++k) {
    const float inv = 1.0f / (0.4f * (float)k);
#pragma unroll
    for (int m = 0; m + k < 11; ++m) {
      const float gm = 0.4f * (float)(m - 3) - 1.0f;
      const float gmk1 = 0.4f * (float)(m + k - 2) - 1.0f;
      b[m] = (xv - gm) * inv * b[m] + (gmk1 - xv) * inv * b[m + 1];
    }
  }
  bf16* p = basis + (size_t)n * 6912 + i * 9;
#pragma unroll
  for (int f = 0; f < 8; ++f) p[f] = __float2bfloat16(b[f]);
  p[8] = __float2bfloat16(xv / (1.0f + __expf(-xv)));
}

__global__ __launch_bounds__(256) void combine4_kernel(
    const float4* __restrict__ p, float4* __restrict__ out) {
  const int idx = blockIdx.x * 256 + (int)threadIdx.x;
  const float4 a = p[idx];
  const float4 b = p[idx + 524288];
  const float4 c = p[idx + 1048576];
  const float4 d = p[idx + 1572864];
  out[idx] =
      make_float4(a.x + b.x + c.x + d.x, a.y + b.y + c.y + d.y,
                  a.z + b.z + c.z + d.z, a.w + b.w + c.w + d.w);
}

// combine 6 bf16 partial slices (stride 2,097,152 elements) -> fp32 out
__global__ __launch_bounds__(256) void combine6b_kernel(
    const bf16* __restrict__ p, float4* __restrict__ out) {
  const int idx = blockIdx.x * 256 + (int)threadIdx.x;  // 0..524287
  float a0 = 0.f, a1 = 0.f, a2 = 0.f, a3 = 0.f;
#pragma unroll
  for (int j = 0; j < 6; ++j) {
    const bf16* q = p + (size_t)j * 2097152 + (size_t)idx * 4;
    a0 += __bfloat162float(q[0]);
    a1 += __bfloat162float(q[1]);
    a2 += __bfloat162float(q[2]);
    a3 += __bfloat162float(q[3]);
  }
  out[idx] = make_float4(a0, a1, a2, a3);
}

// ---------------------------------------------------------------------------
extern "C" void kernel_launch(void* const* d_in, const int* in_sizes, int n_in,
                              void* d_out, int out_size, void* d_ws,
                              size_t ws_size, hipStream_t stream) {
  const float* tok[3] = {(const float*)d_in[0], (const float*)d_in[1],
                         (const float*)d_in[2]};
  const float* wq = (const float*)d_in[3];
  const float* bq = (const float*)d_in[4];
  const float* wk = (const float*)d_in[5];
  const float* bk = (const float*)d_in[6];
  const float* wv = (const float*)d_in[7];
  const float* bv = (const float*)d_in[8];
  // d_in[9] view_emb unused (softmax-invariant)
  const float* lng[3] = {(const float*)d_in[10], (const float*)d_in[12],
                         (const float*)d_in[14]};
  const float* lnb[3] = {(const float*)d_in[11], (const float*)d_in[13],
                         (const float*)d_in[15]};
  const float* bw = (const float*)d_in[16];
  const float* sw = (const float*)d_in[17];
  const float* scaler = (const float*)d_in[18];

  // fused layout (R13, total 169,085,952 B <= known-safe 194,776,064):
  //   basis @0 (113,246,208) -- written by resid_ln3 AFTER attention; until
  //     then sub-aliased: tokb @0 | qkv @12,582,912 | vT @50,331,648
  //   attb (bf16 partials, 24 x 2,097,152 B) @113,246,208 -> 163,577,856
  //   lpart_f @163,577,856 (now 786,432 B used) -> 165,150,720
  //   Wmat @165,150,720 | wqkvb @168,689,664 | bqkv @169,082,880
  //   poutb (KAN z=6, bf16, 25.2MB) aliases attb (dead after resid_ln3)
  // fallback (unchanged): Pb @62,914,560 | lpart @130,023,424 |
  //   attp @132,120,576 | x @165,675,008 | basis aliases [0,..) |
  //   Wmat @190,840,832 | pout aliases attp.
  const bool fused = ws_size >= 169085952ull;
  char* w8 = (char*)d_ws;
  bf16* tokb = (bf16*)(w8 + 0);
  bf16* qkv = (bf16*)(w8 + 12582912);
  bf16* vT = (bf16*)(w8 + 50331648);
  float* x;
  bf16* basis;
  bf16* Wmat;
  // fallback pointers
  bf16* Pb = (bf16*)(w8 + 62914560);
  float* lpart = (float*)(w8 + 130023424);
  float* attp = (float*)(w8 + 132120576);
  float* pout = attp;  // fallback KAN partials (fp32)
  // fused pointers
  bf16* attb = (bf16*)(w8 + 113246208);
  float* lpart_f = (float*)(w8 + 163577856);
  bf16* poutb = (bf16*)(w8 + 113246208);  // bf16 KAN partials, attb dead
  if (fused) {
    x = nullptr;
    basis = (bf16*)(w8 + 0);
    Wmat = (bf16*)(w8 + 165150720);
  } else {
    x = (float*)(w8 + 165675008);
    basis = (bf16*)(w8 + 0);
    Wmat = (bf16*)(w8 + 190840832);
  }
  bf16* wqkvb = (bf16*)((char*)Wmat + 3538944);
  float* bqkv = (float*)((char*)wqkvb + 393216);

  prep_all<<<7168, 256, 0, stream>>>(bw, sw, scaler, Wmat, wq, wk, wv, bq, bk,
                                     bv, wqkvb, bqkv, (const float4*)tok[0],
                                     (const float4*)tok[1],
                                     (const float4*)tok[2], tokb);

  // QKV all views: [24576,256] @ [768,256]^T + bias -> qkv bf16
  mfma_gemm_bt<bf16, false><<<dim3(6, 192, 1), 256, 0, stream>>>(
      tokb, wqkvb, bqkv, qkv, nullptr, 256, 256, 256, 768, 1, 0, 0, 0, 0, 0,
      0, 1.0f);
  transpose_v<<<dim3(64, 4, 6), 256, 0, stream>>>(qkv, vT);

  if (fused) {
    // fused flash attention: 4-wave blocks, 2 blocks/CU
    fused_attn<<<dim3(64, 24), 256, 0, stream>>>(qkv, vT, attb, lpart_f);
    // residual + LN + basis, all 3 views in one dispatch
    resid_ln3<<<24576, 256, 0, stream>>>(attb, lpart_f, tok[0], tok[1],
                                         tok[2], lng[0], lng[1], lng[2],
                                         lnb[0], lnb[1], lnb[2], basis);
    // KAN split-K=6 (z=6, 768 blocks = 3/CU), bf16 partials
    mfma_gemm_bt<bf16, false><<<dim3(2, 64, 6), 256, 0, stream>>>(
        basis, Wmat, nullptr, poutb, nullptr, 1152, 6912, 6912, 256, 3, 0,
        1152, 0, 1152, 2097152, 0, 1.0f);
    combine6b_kernel<<<2048, 256, 0, stream>>>(poutb, (float4*)d_out);
  } else {
    for (int v = 0; v < 3; ++v) {
      const bf16* qb = qkv + (size_t)(2 * v) * 4096 * 768;
      // scores both batches (z=2): P = exp(q@k^T/16) bf16 + lpart partials
      mfma_gemm_bt<bf16, true><<<dim3(32, 32, 2), 256, 0, stream>>>(
          qb, qb + 256, nullptr, Pb, lpart, 256, 768, 768, 4096, 1, 0,
          3145728, 0, 3145728, 16777216, 262144, 0.0625f);
      // PV split-K=4 x batch (z=8): attp[z] = P-slice @ vT-slice^T
      mfma_gemm_bt<float, false><<<dim3(2, 32, 8), 256, 0, stream>>>(
          Pb, vT + (size_t)(2 * v) * 1048576, nullptr, attp, nullptr, 1024,
          4096, 4096, 256, 2, 16777216, 1024, 1048576, 1024, 1048576, 0, 1.0f);
      resid_ln_kernel<<<8192, 256, 0, stream>>>(attp, lpart, tok[v], lng[v],
                                                lnb[v], x, 64, v);
    }
    basis_kernel<<<dim3(3, 8192), 256, 0, stream>>>(x, basis);
    mfma_gemm_bt<float, false><<<dim3(2, 64, 4), 256, 0, stream>>>(
        basis, Wmat, nullptr, pout, nullptr, 1728, 6912, 6912, 256, 2, 0,
        1728, 0, 1728, 2097152, 0, 1.0f);
    combine4_kernel<<<2048, 256, 0, stream>>>((const float4*)pout,
                                              (float4*)d_out);
  }
}